// Round 5
// baseline (1749.242 us; speedup 1.0000x reference)
//
#include <hip/hip_runtime.h>
#include <hip/hip_bf16.h>
#include <math.h>

#define B_ 4
#define S_ 1024
#define D_ 512
#define H_ 8
#define L_ 4
#define DFF_ 2048
#define V_ 32000
#define DK_ 64
#define KTOP 307
#define SCW 1036    // score row stride (words); P overlays words 0..517 of SAME row
#define PST 2072    // P row stride in bf16 elems (= SCW*2)

using bf16x8 = __attribute__((ext_vector_type(8))) __bf16;
using bf16x4 = __attribute__((ext_vector_type(4))) __bf16;
using bf16x2 = __attribute__((ext_vector_type(2))) __bf16;
using f32x4v = __attribute__((ext_vector_type(4))) float;

__device__ __forceinline__ void gload_lds16(const __bf16* g, __bf16* l) {
  __builtin_amdgcn_global_load_lds(
      (const __attribute__((address_space(1))) void*)g,
      (__attribute__((address_space(3))) void*)l, 16, 0, 0);
}

// ---------------- embedding: h = tok_emb[x] + pos_emb ----------------
__global__ void embed_kernel(const int* __restrict__ x, const float* __restrict__ tok,
                             const float* __restrict__ pos, float* __restrict__ h) {
  int row = blockIdx.x;
  int t = threadIdx.x;             // 128 threads x float4 = 512
  int s = row & (S_ - 1);
  int token = x[row];
  const float4* t4 = reinterpret_cast<const float4*>(tok + (size_t)token * D_);
  const float4* p4 = reinterpret_cast<const float4*>(pos + (size_t)s * D_);
  float4 a = t4[t];
  float4 b = p4[t];
  a.x += b.x; a.y += b.y; a.z += b.z; a.w += b.w;
  reinterpret_cast<float4*>(h + (size_t)row * D_)[t] = a;
}

// ---------------- layernorm (one block per row, D=512), bf16 out ----------------
__global__ void ln_kernel(const float* __restrict__ xin, const float* __restrict__ g,
                          const float* __restrict__ bta, __bf16* __restrict__ y) {
  int row = blockIdx.x;
  int t = threadIdx.x;             // 256 threads x float2
  const float2* x2 = reinterpret_cast<const float2*>(xin + (size_t)row * D_);
  float2 v = x2[t];
  float s = v.x + v.y;
  #pragma unroll
  for (int m = 1; m < 64; m <<= 1) s += __shfl_xor(s, m, 64);
  __shared__ float red[4];
  __shared__ float red2[4];
  int wid = t >> 6, lane = t & 63;
  if (lane == 0) red[wid] = s;
  __syncthreads();
  float mu = (red[0] + red[1] + red[2] + red[3]) * (1.0f / D_);
  float dx = v.x - mu, dy = v.y - mu;
  float s2 = dx * dx + dy * dy;
  #pragma unroll
  for (int m = 1; m < 64; m <<= 1) s2 += __shfl_xor(s2, m, 64);
  if (lane == 0) red2[wid] = s2;
  __syncthreads();
  float var = (red2[0] + red2[1] + red2[2] + red2[3]) * (1.0f / D_);
  float rstd = rsqrtf(var + 1e-5f);
  float2 gg = reinterpret_cast<const float2*>(g)[t];
  float2 bb = reinterpret_cast<const float2*>(bta)[t];
  bf16x2 o2;
  o2[0] = (__bf16)(dx * rstd * gg.x + bb.x);
  o2[1] = (__bf16)(dy * rstd * gg.y + bb.y);
  *reinterpret_cast<bf16x2*>(y + (size_t)row * D_ + t * 2) = o2;
}

// ------------- transpose fp32 [Kd][N] -> bf16 [N][Kd], batched over z -------------
__global__ void transpose_bf16_kernel(const float* __restrict__ in, __bf16* __restrict__ out,
                                      int Kd, int N, long in_bstride, long out_bstride) {
  __shared__ float tile[32][33];
  const float* ib = in + (size_t)blockIdx.z * in_bstride;
  __bf16* ob = out + (size_t)blockIdx.z * out_bstride;
  int n0 = blockIdx.x * 32, k0 = blockIdx.y * 32;
  int tx = threadIdx.x & 31, ty = threadIdx.x >> 5;   // 32x8
  #pragma unroll
  for (int i = 0; i < 4; ++i)
    tile[ty + i * 8][tx] = ib[(size_t)(k0 + ty + i * 8) * N + n0 + tx];
  __syncthreads();
  #pragma unroll
  for (int i = 0; i < 4; ++i)
    ob[(size_t)(n0 + ty + i * 8) * Kd + k0 + tx] = (__bf16)tile[tx][ty + i * 8];
}

// ---------------- bias concat for fused QKV ----------------
__global__ void concat_bias_kernel(const float* __restrict__ bq, const float* __restrict__ bk,
                                   const float* __restrict__ bv, float* __restrict__ bqkv) {
  int i = blockIdx.x * 256 + threadIdx.x;   // L_*1536
  int l = i / 1536, c = i - l * 1536;
  float v = (c < 512) ? bq[l * 512 + c]
          : (c < 1024) ? bk[l * 512 + c - 512]
                       : bv[l * 512 + c - 1024];
  bqkv[i] = v;
}

// ---------------- bf16 MFMA GEMM (m97 structure), 128x128 tile ----------------
// OMODE: 0 fp32 out | 1 bf16 out | 3 fp32 out + bf16 out2 | 4 fused-QKV
#define BM 128
#define BN 128
#define BK 32

template<int OMODE, bool GELU_ACT, bool RES, bool SWZ>
__global__ __launch_bounds__(256)
void gemm_bf16_kernel(const __bf16* __restrict__ A, const __bf16* __restrict__ WT,
                      const float* __restrict__ bias, const float* __restrict__ res,
                      void* __restrict__ outp, void* __restrict__ outp2, void* __restrict__ outp3,
                      int M, int N, int Kd) {
  __shared__ __bf16 As[BM * BK];
  __shared__ __bf16 Ws[BN * BK];
  int tid = threadIdx.x;
  int lane = tid & 63, w = tid >> 6;
  int wr = w >> 1, wc = w & 1;
  int lr = lane & 15, lg = lane >> 4;
  int bx, by;
  if (SWZ) {   // XCD-bijective swizzle (nwg % 8 == 0): consecutive swz on one XCD
    int lid = blockIdx.x;
    int cpx = gridDim.x >> 3;
    int swz = (lid & 7) * cpx + (lid >> 3);
    int gx = M >> 7;
    bx = swz % gx;
    by = swz / gx;
  } else {
    bx = blockIdx.x; by = blockIdx.y;
  }
  int row0 = bx * BM, col0 = by * BN;

  int srow = lane >> 2;        // 0..15 row within 16-row stripe
  int schunk = lane & 3;       // 16B chunk within a 64B row
  const __bf16* Abase = A + (size_t)(row0 + srow) * Kd + schunk * 8;
  const __bf16* Wbase = WT + (size_t)(col0 + srow) * Kd + schunk * 8;

  f32x4v acc[4][4];
  #pragma unroll
  for (int i = 0; i < 4; ++i)
    #pragma unroll
    for (int j = 0; j < 4; ++j)
      #pragma unroll
      for (int e = 0; e < 4; ++e) acc[i][j][e] = 0.0f;

  for (int k0 = 0; k0 < Kd; k0 += BK) {
    #pragma unroll
    for (int p = 0; p < 2; ++p) {
      int r0 = p * 64 + w * 16;
      gload_lds16(Abase + (size_t)r0 * Kd + k0, &As[r0 * BK]);
      gload_lds16(Wbase + (size_t)r0 * Kd + k0, &Ws[r0 * BK]);
    }
    __syncthreads();
    bf16x8 af[4], bfr[4];
    #pragma unroll
    for (int mr = 0; mr < 4; ++mr)
      af[mr] = *reinterpret_cast<const bf16x8*>(&As[(wr * 64 + mr * 16 + lr) * BK + lg * 8]);
    #pragma unroll
    for (int nc = 0; nc < 4; ++nc)
      bfr[nc] = *reinterpret_cast<const bf16x8*>(&Ws[(wc * 64 + nc * 16 + lr) * BK + lg * 8]);
    #pragma unroll
    for (int mr = 0; mr < 4; ++mr)
      #pragma unroll
      for (int nc = 0; nc < 4; ++nc)
        acc[mr][nc] = __builtin_amdgcn_mfma_f32_16x16x32_bf16(af[mr], bfr[nc], acc[mr][nc], 0, 0, 0);
    __syncthreads();
  }

  #pragma unroll
  for (int mr = 0; mr < 4; ++mr) {
    #pragma unroll
    for (int nc = 0; nc < 4; ++nc) {
      int c = col0 + wc * 64 + nc * 16 + lr;
      int rb = row0 + wr * 64 + mr * 16 + lg * 4;
      float vv[4];
      #pragma unroll
      for (int j = 0; j < 4; ++j) {
        float t = acc[mr][nc][j] + bias[c];
        if (RES) t += res[(size_t)(rb + j) * N + c];
        if (GELU_ACT) t = 0.5f * t * (1.0f + erff(t * 0.70710678118654752f));
        vv[j] = t;
      }
      if (OMODE == 0) {
        float* out = (float*)outp;
        #pragma unroll
        for (int j = 0; j < 4; ++j) out[(size_t)(rb + j) * N + c] = vv[j];
      } else if (OMODE == 1) {
        __bf16* out = (__bf16*)outp;
        #pragma unroll
        for (int j = 0; j < 4; ++j) out[(size_t)(rb + j) * N + c] = (__bf16)vv[j];
      } else if (OMODE == 3) {
        float* out = (float*)outp;
        __bf16* out2 = (__bf16*)outp2;
        #pragma unroll
        for (int j = 0; j < 4; ++j) {
          out[(size_t)(rb + j) * N + c] = vv[j];
          out2[(size_t)(rb + j) * N + c] = (__bf16)vv[j];
        }
      } else {  // OMODE 4: fused QKV epilogue
        if (col0 < 512) {
          __bf16* out = (__bf16*)outp;
          #pragma unroll
          for (int j = 0; j < 4; ++j) out[(size_t)(rb + j) * D_ + c] = (__bf16)vv[j];
        } else if (col0 < 1024) {
          __bf16* out = (__bf16*)outp2;
          #pragma unroll
          for (int j = 0; j < 4; ++j) out[(size_t)(rb + j) * D_ + (c - 512)] = (__bf16)vv[j];
        } else {
          __bf16* out = (__bf16*)outp3;   // vt [B][D][S]
          int b = rb >> 10, s0 = rb & (S_ - 1);
          bf16x4 pk;
          #pragma unroll
          for (int j = 0; j < 4; ++j) pk[j] = (__bf16)vv[j];
          *reinterpret_cast<bf16x4*>(&out[((size_t)b * D_ + (c - 1024)) * S_ + s0]) = pk;
        }
      }
    }
  }
}

// ---------------- 64x128-tile GEMM for N=512 shapes (Wo, W2) -> 256 workgroups ----------------
template<int OMODE, bool RES>
__global__ __launch_bounds__(256)
void gemm64_kernel(const __bf16* __restrict__ A, const __bf16* __restrict__ WT,
                   const float* __restrict__ bias, const float* __restrict__ res,
                   void* __restrict__ outp, void* __restrict__ outp2,
                   int M, int N, int Kd) {
  __shared__ __bf16 As[64 * BK];
  __shared__ __bf16 Ws[BN * BK];
  int tid = threadIdx.x;
  int lane = tid & 63, w = tid >> 6;
  int wr = w >> 1, wc = w & 1;              // 2x2 waves, each 32x64
  int lr = lane & 15, lg = lane >> 4;
  int row0 = blockIdx.x * 64, col0 = blockIdx.y * BN;

  int srow = lane >> 2;
  int schunk = lane & 3;
  const __bf16* Abase = A + (size_t)(row0 + srow) * Kd + schunk * 8;
  const __bf16* Wbase = WT + (size_t)(col0 + srow) * Kd + schunk * 8;

  f32x4v acc[2][4];
  #pragma unroll
  for (int i = 0; i < 2; ++i)
    #pragma unroll
    for (int j = 0; j < 4; ++j)
      #pragma unroll
      for (int e = 0; e < 4; ++e) acc[i][j][e] = 0.0f;

  for (int k0 = 0; k0 < Kd; k0 += BK) {
    gload_lds16(Abase + (size_t)(w * 16) * Kd + k0, &As[w * 16 * BK]);
    #pragma unroll
    for (int p = 0; p < 2; ++p) {
      int r0 = p * 64 + w * 16;
      gload_lds16(Wbase + (size_t)r0 * Kd + k0, &Ws[r0 * BK]);
    }
    __syncthreads();
    bf16x8 af[2], bfr[4];
    #pragma unroll
    for (int mr = 0; mr < 2; ++mr)
      af[mr] = *reinterpret_cast<const bf16x8*>(&As[(wr * 32 + mr * 16 + lr) * BK + lg * 8]);
    #pragma unroll
    for (int nc = 0; nc < 4; ++nc)
      bfr[nc] = *reinterpret_cast<const bf16x8*>(&Ws[(wc * 64 + nc * 16 + lr) * BK + lg * 8]);
    #pragma unroll
    for (int mr = 0; mr < 2; ++mr)
      #pragma unroll
      for (int nc = 0; nc < 4; ++nc)
        acc[mr][nc] = __builtin_amdgcn_mfma_f32_16x16x32_bf16(af[mr], bfr[nc], acc[mr][nc], 0, 0, 0);
    __syncthreads();
  }

  #pragma unroll
  for (int mr = 0; mr < 2; ++mr) {
    #pragma unroll
    for (int nc = 0; nc < 4; ++nc) {
      int c = col0 + wc * 64 + nc * 16 + lr;
      int rb = row0 + wr * 32 + mr * 16 + lg * 4;
      float vv[4];
      #pragma unroll
      for (int j = 0; j < 4; ++j) {
        float t = acc[mr][nc][j] + bias[c];
        if (RES) t += res[(size_t)(rb + j) * N + c];
        vv[j] = t;
      }
      if (OMODE == 0) {
        float* out = (float*)outp;
        #pragma unroll
        for (int j = 0; j < 4; ++j) out[(size_t)(rb + j) * N + c] = vv[j];
      } else {  // OMODE 3
        float* out = (float*)outp;
        __bf16* out2 = (__bf16*)outp2;
        #pragma unroll
        for (int j = 0; j < 4; ++j) {
          out[(size_t)(rb + j) * N + c] = vv[j];
          out2[(size_t)(rb + j) * N + c] = (__bf16)vv[j];
        }
      }
    }
  }
}

// ---------------- fused attention: MFMA scores -> top-307 -> softmax -> MFMA PV ----------------
// 16 q-rows per block, 4 waves, 2048 blocks. XCD-swizzled so each XCD owns 4 (b,h)
// groups exclusively -> K/V slices L2-resident (1 MB working set per XCD).
__global__ __launch_bounds__(256)
void attn_kernel(const __bf16* __restrict__ qm, const __bf16* __restrict__ km,
                 const __bf16* __restrict__ vt, __bf16* __restrict__ o) {
  __shared__ unsigned int sc[16][SCW];   // fp32-mapped scores; row r's P overlays its own words 0..517
  __shared__ float rs[16];
  // ---- XCD-locality swizzle: grp = (b,h) in 0..31; 4 grps per XCD ----
  int bid = blockIdx.x;                  // 0..2047
  int xcd = bid & 7;
  int slot = bid >> 3;                   // 0..255
  int grp = xcd * 4 + (slot >> 6);       // 0..31
  int qblk = slot & 63;
  int bb = grp >> 3, hh = grp & 7;
  int q0 = qblk * 16;

  const int tid = threadIdx.x;
  const int lane = tid & 63, w = tid >> 6;
  const int lr = lane & 15, lg = lane >> 4;

  const __bf16* qrow = qm + ((size_t)(bb * S_ + q0 + lr)) * D_ + hh * DK_;
  bf16x8 qf0 = *reinterpret_cast<const bf16x8*>(qrow + lg * 8);
  bf16x8 qf1 = *reinterpret_cast<const bf16x8*>(qrow + 32 + lg * 8);

  // ---- phase 1: scores via MFMA, K fragments straight from global (L2-resident) ----
  const __bf16* kbase = km + ((size_t)bb * S_) * D_ + hh * DK_;
  #pragma unroll 4
  for (int kt = 0; kt < 16; ++kt) {
    int key0 = kt * 64 + w * 16;
    const __bf16* krow = kbase + (size_t)(key0 + lr) * D_;
    bf16x8 kf0 = *reinterpret_cast<const bf16x8*>(krow + lg * 8);
    bf16x8 kf1 = *reinterpret_cast<const bf16x8*>(krow + 32 + lg * 8);
    f32x4v d = {0.0f, 0.0f, 0.0f, 0.0f};
    d = __builtin_amdgcn_mfma_f32_16x16x32_bf16(qf0, kf0, d, 0, 0, 0);
    d = __builtin_amdgcn_mfma_f32_16x16x32_bf16(qf1, kf1, d, 0, 0, 0);
    #pragma unroll
    for (int j = 0; j < 4; ++j) {
      float s = d[j] * 0.125f;
      unsigned int u = __float_as_uint(s);
      u = (u & 0x80000000u) ? ~u : (u | 0x80000000u);   // monotone map
      sc[lg * 4 + j][key0 + lr] = u;
    }
  }
  __syncthreads();

  // ---- phase 2: one WAVE per row (4 rows per wave, sequential); ballot-based count ----
  #pragma unroll
  for (int rr = 0; rr < 4; ++rr) {
    int r = w * 4 + rr;
    unsigned int uv[16];
    #pragma unroll
    for (int k = 0; k < 4; ++k) {
      uint4 t4 = *reinterpret_cast<const uint4*>(&sc[r][lane * 4 + k * 256]);
      uv[k * 4 + 0] = t4.x; uv[k * 4 + 1] = t4.y;
      uv[k * 4 + 2] = t4.z; uv[k * 4 + 3] = t4.w;
    }
    unsigned int umax = 0u;
    #pragma unroll
    for (int i = 0; i < 16; ++i) umax = uv[i] > umax ? uv[i] : umax;
    #pragma unroll
    for (int m = 1; m < 64; m <<= 1) {
      unsigned int other = (unsigned int)__shfl_xor((int)umax, m, 64);
      umax = other > umax ? other : umax;
    }
    // 307th-largest threshold: binary search, wave-uniform count via ballot+popc
    unsigned int lo = 0u;
    for (int bit = 31; bit >= 0; --bit) {
      unsigned int c = lo | (1u << bit);
      int cnt = 0;
      #pragma unroll
      for (int i = 0; i < 16; ++i)
        cnt += (int)__popcll(__ballot(uv[i] >= c));
      if (cnt >= KTOP) lo = c;
    }
    unsigned int ubm = (umax & 0x80000000u) ? (umax ^ 0x80000000u) : ~umax;
    float mval = __uint_as_float(ubm);

    asm volatile("" ::: "memory");   // keep P stores after the sc reads above
    __bf16* P = reinterpret_cast<__bf16*>(&sc[r][0]);   // overlays row r only
    float lsum = 0.0f;
    #pragma unroll
    for (int k = 0; k < 4; ++k) {
      bf16x4 pk;
      #pragma unroll
      for (int e = 0; e < 4; ++e) {
        unsigned int u = uv[k * 4 + e];
        float p = 0.0f;
        if (u >= lo) {
          unsigned int ub = (u & 0x80000000u) ? (u ^ 0x80000000u) : ~u;
          p = __expf(__uint_as_float(ub) - mval);
        }
        pk[e] = (__bf16)p;
        lsum += (float)pk[e];
      }
      *reinterpret_cast<bf16x4*>(&P[lane * 4 + k * 256]) = pk;
    }
    #pragma unroll
    for (int m = 1; m < 64; m <<= 1) lsum += __shfl_xor(lsum, m, 64);
    if (lane == 0) rs[r] = lsum;
  }
  __syncthreads();

  // ---- phase 3: o = (P @ V) / rowsum via MFMA; V^T fragments straight from global ----
  {
    const __bf16* P = reinterpret_cast<const __bf16*>(&sc[0][0]);
    const __bf16* vbase = vt + ((size_t)bb * D_ + hh * DK_ + w * 16 + lr) * S_;
    const __bf16* prow = P + (size_t)lr * PST;
    f32x4v oacc = {0.0f, 0.0f, 0.0f, 0.0f};
    #pragma unroll 4
    for (int kt = 0; kt < 32; ++kt) {
      bf16x8 a = *reinterpret_cast<const bf16x8*>(prow + kt * 32 + lg * 8);
      bf16x8 b = *reinterpret_cast<const bf16x8*>(vbase + kt * 32 + lg * 8);
      oacc = __builtin_amdgcn_mfma_f32_16x16x32_bf16(a, b, oacc, 0, 0, 0);
    }
    #pragma unroll
    for (int j = 0; j < 4; ++j) {
      int qr = lg * 4 + j;
      float ov = oacc[j] / rs[qr];
      o[((size_t)(bb * S_ + q0 + qr)) * D_ + hh * DK_ + w * 16 + lr] = (__bf16)ov;
    }
  }
}

extern "C" void kernel_launch(void* const* d_in, const int* in_sizes, int n_in,
                              void* d_out, int out_size, void* d_ws, size_t ws_size,
                              hipStream_t stream) {
  (void)in_sizes; (void)n_in; (void)out_size; (void)ws_size;
  const int*   x    = (const int*)d_in[0];
  const float* tok  = (const float*)d_in[1];
  const float* pos  = (const float*)d_in[2];
  const float* Wq   = (const float*)d_in[3];
  const float* bq   = (const float*)d_in[4];
  const float* Wk   = (const float*)d_in[5];
  const float* bk   = (const float*)d_in[6];
  const float* Wv   = (const float*)d_in[7];
  const float* bv   = (const float*)d_in[8];
  const float* Wo   = (const float*)d_in[9];
  const float* bo   = (const float*)d_in[10];
  const float* g1   = (const float*)d_in[11];
  const float* be1  = (const float*)d_in[12];
  const float* g2   = (const float*)d_in[13];
  const float* be2  = (const float*)d_in[14];
  const float* W1   = (const float*)d_in[15];
  const float* b1   = (const float*)d_in[16];
  const float* Wm   = (const float*)d_in[17];
  const float* bm   = (const float*)d_in[18];
  const float* W2   = (const float*)d_in[19];
  const float* b2   = (const float*)d_in[20];
  const float* Wout = (const float*)d_in[21];
  const float* bout = (const float*)d_in[22];
  float* logits = (float*)d_out;

  const int M = B_ * S_;  // 4096
  float* ws = (float*)d_ws;
  float* h    = ws;                                   // fp32 [M][D]
  float* bqkv = h + (size_t)M * D_;                   // fp32 [L][1536]
  __bf16* y16  = (__bf16*)(bqkv + (size_t)L_ * 1536);
  __bf16* f1b  = y16  + (size_t)M * D_;
  __bf16* f2b  = f1b  + (size_t)M * DFF_;
  __bf16* qb16 = f2b  + (size_t)M * DFF_;
  __bf16* kb16 = qb16 + (size_t)M * D_;
  __bf16* vt16 = kb16 + (size_t)M * D_;               // [B][D][S]
  __bf16* ob16 = vt16 + (size_t)M * D_;
  __bf16* h16  = ob16 + (size_t)M * D_;
  __bf16* WqkvT = h16 + (size_t)M * D_;               // [l][1536][512]
  __bf16* WoT  = WqkvT + (size_t)L_ * 1536 * D_;
  __bf16* W1T  = WoT  + (size_t)L_ * D_ * D_;         // [l][DFF][D]
  __bf16* WmT  = W1T  + (size_t)L_ * D_ * DFF_;       // [l][DFF][DFF]
  __bf16* W2T  = WmT  + (size_t)L_ * DFF_ * DFF_;     // [l][D][DFF]
  __bf16* WoutT = W2T + (size_t)L_ * D_ * DFF_;       // [V][D]

  const long DD = (long)D_ * D_;
  transpose_bf16_kernel<<<dim3(D_/32,  D_/32,   L_), 256, 0, stream>>>(Wq, WqkvT,            D_, D_, DD, 1536L*D_);
  transpose_bf16_kernel<<<dim3(D_/32,  D_/32,   L_), 256, 0, stream>>>(Wk, WqkvT + 512*512,  D_, D_, DD, 1536L*D_);
  transpose_bf16_kernel<<<dim3(D_/32,  D_/32,   L_), 256, 0, stream>>>(Wv, WqkvT + 1024*512, D_, D_, DD, 1536L*D_);
  transpose_bf16_kernel<<<dim3(D_/32,  D_/32,   L_), 256, 0, stream>>>(Wo, WoT, D_, D_, DD, DD);
  transpose_bf16_kernel<<<dim3(DFF_/32, D_/32,  L_), 256, 0, stream>>>(W1, W1T, D_, DFF_, (long)D_*DFF_, (long)D_*DFF_);
  transpose_bf16_kernel<<<dim3(DFF_/32, DFF_/32,L_), 256, 0, stream>>>(Wm, WmT, DFF_, DFF_, (long)DFF_*DFF_, (long)DFF_*DFF_);
  transpose_bf16_kernel<<<dim3(D_/32,  DFF_/32, L_), 256, 0, stream>>>(W2, W2T, DFF_, D_, (long)D_*DFF_, (long)D_*DFF_);
  transpose_bf16_kernel<<<dim3(V_/32,  D_/32,   1 ), 256, 0, stream>>>(Wout, WoutT, D_, V_, (long)D_*V_, (long)D_*V_);
  concat_bias_kernel<<<(L_*1536)/256, 256, 0, stream>>>(bq, bk, bv, bqkv);

  embed_kernel<<<M, 128, 0, stream>>>(x, tok, pos, h);

  for (int l = 0; l < L_; ++l) {
    ln_kernel<<<M, 256, 0, stream>>>(h, g1 + l * D_, be1 + l * D_, y16);
    gemm_bf16_kernel<4,false,false,true><<<dim3((M/BM) * (1536/BN)), 256, 0, stream>>>(
        y16, WqkvT + (size_t)l * 1536 * D_, bqkv + l * 1536, nullptr,
        qb16, kb16, vt16, M, 1536, D_);
    attn_kernel<<<dim3(2048), 256, 0, stream>>>(qb16, kb16, vt16, ob16);
    gemm64_kernel<0,true><<<dim3(M/64, D_/BN), 256, 0, stream>>>(
        ob16, WoT + (size_t)l * DD, bo + l * D_, h, h, nullptr, M, D_, D_);
    ln_kernel<<<M, 256, 0, stream>>>(h, g2 + l * D_, be2 + l * D_, y16);
    gemm_bf16_kernel<1,true,false,true><<<dim3((M/BM) * (DFF_/BN)), 256, 0, stream>>>(
        y16, W1T + (size_t)l * D_ * DFF_, b1 + l * DFF_, nullptr, f1b, nullptr, nullptr, M, DFF_, D_);
    gemm_bf16_kernel<1,true,false,true><<<dim3((M/BM) * (DFF_/BN)), 256, 0, stream>>>(
        f1b, WmT + (size_t)l * DFF_ * DFF_, bm + l * DFF_, nullptr, f2b, nullptr, nullptr, M, DFF_, DFF_);
    gemm64_kernel<3,true><<<dim3(M/64, D_/BN), 256, 0, stream>>>(
        f2b, W2T + (size_t)l * D_ * DFF_, b2 + l * D_, h, h, h16, M, D_, DFF_);
  }
  gemm_bf16_kernel<0,false,false,true><<<dim3((M/BM) * (V_/BN)), 256, 0, stream>>>(
      h16, WoutT, bout, nullptr, logits, nullptr, nullptr, M, V_, D_);
}

// Round 6
// 1407.601 us; speedup vs baseline: 1.2427x; 1.2427x over previous
//
#include <hip/hip_runtime.h>
#include <hip/hip_bf16.h>
#include <math.h>

#define B_ 4
#define S_ 1024
#define D_ 512
#define H_ 8
#define L_ 4
#define DFF_ 2048
#define V_ 32000
#define DK_ 64
#define KTOP 307
#define SRS 1048    // score row stride in u16 elems (pad 24: rows offset 12 banks)

using bf16x8 = __attribute__((ext_vector_type(8))) __bf16;
using bf16x4 = __attribute__((ext_vector_type(4))) __bf16;
using bf16x2 = __attribute__((ext_vector_type(2))) __bf16;
using f32x4v = __attribute__((ext_vector_type(4))) float;

__device__ __forceinline__ void gload_lds16(const __bf16* g, __bf16* l) {
  __builtin_amdgcn_global_load_lds(
      (const __attribute__((address_space(1))) void*)g,
      (__attribute__((address_space(3))) void*)l, 16, 0, 0);
}

// fp32 -> bf16 bits (RNE), as low 16 of u32
__device__ __forceinline__ unsigned int f32_to_bf16_bits(float s) {
  unsigned int x = __float_as_uint(s);
  return (x + 0x7FFFu + ((x >> 16) & 1u)) >> 16;
}

// ---------------- embedding: h = tok_emb[x] + pos_emb ----------------
__global__ void embed_kernel(const int* __restrict__ x, const float* __restrict__ tok,
                             const float* __restrict__ pos, float* __restrict__ h) {
  int row = blockIdx.x;
  int t = threadIdx.x;             // 128 threads x float4 = 512
  int s = row & (S_ - 1);
  int token = x[row];
  const float4* t4 = reinterpret_cast<const float4*>(tok + (size_t)token * D_);
  const float4* p4 = reinterpret_cast<const float4*>(pos + (size_t)s * D_);
  float4 a = t4[t];
  float4 b = p4[t];
  a.x += b.x; a.y += b.y; a.z += b.z; a.w += b.w;
  reinterpret_cast<float4*>(h + (size_t)row * D_)[t] = a;
}

// ---------------- layernorm (one block per row, D=512), bf16 out ----------------
__global__ void ln_kernel(const float* __restrict__ xin, const float* __restrict__ g,
                          const float* __restrict__ bta, __bf16* __restrict__ y) {
  int row = blockIdx.x;
  int t = threadIdx.x;             // 256 threads x float2
  const float2* x2 = reinterpret_cast<const float2*>(xin + (size_t)row * D_);
  float2 v = x2[t];
  float s = v.x + v.y;
  #pragma unroll
  for (int m = 1; m < 64; m <<= 1) s += __shfl_xor(s, m, 64);
  __shared__ float red[4];
  __shared__ float red2[4];
  int wid = t >> 6, lane = t & 63;
  if (lane == 0) red[wid] = s;
  __syncthreads();
  float mu = (red[0] + red[1] + red[2] + red[3]) * (1.0f / D_);
  float dx = v.x - mu, dy = v.y - mu;
  float s2 = dx * dx + dy * dy;
  #pragma unroll
  for (int m = 1; m < 64; m <<= 1) s2 += __shfl_xor(s2, m, 64);
  if (lane == 0) red2[wid] = s2;
  __syncthreads();
  float var = (red2[0] + red2[1] + red2[2] + red2[3]) * (1.0f / D_);
  float rstd = rsqrtf(var + 1e-5f);
  float2 gg = reinterpret_cast<const float2*>(g)[t];
  float2 bb = reinterpret_cast<const float2*>(bta)[t];
  bf16x2 o2;
  o2[0] = (__bf16)(dx * rstd * gg.x + bb.x);
  o2[1] = (__bf16)(dy * rstd * gg.y + bb.y);
  *reinterpret_cast<bf16x2*>(y + (size_t)row * D_ + t * 2) = o2;
}

// ------------- transpose fp32 [Kd][N] -> bf16 [N][Kd], batched over z -------------
__global__ void transpose_bf16_kernel(const float* __restrict__ in, __bf16* __restrict__ out,
                                      int Kd, int N, long in_bstride, long out_bstride) {
  __shared__ float tile[32][33];
  const float* ib = in + (size_t)blockIdx.z * in_bstride;
  __bf16* ob = out + (size_t)blockIdx.z * out_bstride;
  int n0 = blockIdx.x * 32, k0 = blockIdx.y * 32;
  int tx = threadIdx.x & 31, ty = threadIdx.x >> 5;   // 32x8
  #pragma unroll
  for (int i = 0; i < 4; ++i)
    tile[ty + i * 8][tx] = ib[(size_t)(k0 + ty + i * 8) * N + n0 + tx];
  __syncthreads();
  #pragma unroll
  for (int i = 0; i < 4; ++i)
    ob[(size_t)(n0 + ty + i * 8) * Kd + k0 + tx] = (__bf16)tile[tx][ty + i * 8];
}

// ---------------- bias concat for fused QKV ----------------
__global__ void concat_bias_kernel(const float* __restrict__ bq, const float* __restrict__ bk,
                                   const float* __restrict__ bv, float* __restrict__ bqkv) {
  int i = blockIdx.x * 256 + threadIdx.x;   // L_*1536
  int l = i / 1536, c = i - l * 1536;
  float v = (c < 512) ? bq[l * 512 + c]
          : (c < 1024) ? bk[l * 512 + c - 512]
                       : bv[l * 512 + c - 1024];
  bqkv[i] = v;
}

// ---------------- bf16 MFMA GEMM (m97 structure), 128x128 tile ----------------
// OMODE: 0 fp32 out | 1 bf16 out | 3 fp32 out + bf16 out2 | 4 fused-QKV
#define BM 128
#define BN 128
#define BK 32

template<int OMODE, bool GELU_ACT, bool RES, bool SWZ>
__global__ __launch_bounds__(256)
void gemm_bf16_kernel(const __bf16* __restrict__ A, const __bf16* __restrict__ WT,
                      const float* __restrict__ bias, const float* __restrict__ res,
                      void* __restrict__ outp, void* __restrict__ outp2, void* __restrict__ outp3,
                      int M, int N, int Kd) {
  __shared__ __bf16 As[BM * BK];
  __shared__ __bf16 Ws[BN * BK];
  int tid = threadIdx.x;
  int lane = tid & 63, w = tid >> 6;
  int wr = w >> 1, wc = w & 1;
  int lr = lane & 15, lg = lane >> 4;
  int bx, by;
  if (SWZ) {   // XCD-bijective swizzle (nwg % 8 == 0)
    int lid = blockIdx.x;
    int cpx = gridDim.x >> 3;
    int swz = (lid & 7) * cpx + (lid >> 3);
    int gx = M >> 7;
    bx = swz % gx;
    by = swz / gx;
  } else {
    bx = blockIdx.x; by = blockIdx.y;
  }
  int row0 = bx * BM, col0 = by * BN;

  int srow = lane >> 2;        // 0..15 row within 16-row stripe
  int schunk = lane & 3;       // 16B chunk within a 64B row
  const __bf16* Abase = A + (size_t)(row0 + srow) * Kd + schunk * 8;
  const __bf16* Wbase = WT + (size_t)(col0 + srow) * Kd + schunk * 8;

  f32x4v acc[4][4];
  #pragma unroll
  for (int i = 0; i < 4; ++i)
    #pragma unroll
    for (int j = 0; j < 4; ++j)
      #pragma unroll
      for (int e = 0; e < 4; ++e) acc[i][j][e] = 0.0f;

  for (int k0 = 0; k0 < Kd; k0 += BK) {
    #pragma unroll
    for (int p = 0; p < 2; ++p) {
      int r0 = p * 64 + w * 16;
      gload_lds16(Abase + (size_t)r0 * Kd + k0, &As[r0 * BK]);
      gload_lds16(Wbase + (size_t)r0 * Kd + k0, &Ws[r0 * BK]);
    }
    __syncthreads();
    bf16x8 af[4], bfr[4];
    #pragma unroll
    for (int mr = 0; mr < 4; ++mr)
      af[mr] = *reinterpret_cast<const bf16x8*>(&As[(wr * 64 + mr * 16 + lr) * BK + lg * 8]);
    #pragma unroll
    for (int nc = 0; nc < 4; ++nc)
      bfr[nc] = *reinterpret_cast<const bf16x8*>(&Ws[(wc * 64 + nc * 16 + lr) * BK + lg * 8]);
    #pragma unroll
    for (int mr = 0; mr < 4; ++mr)
      #pragma unroll
      for (int nc = 0; nc < 4; ++nc)
        acc[mr][nc] = __builtin_amdgcn_mfma_f32_16x16x32_bf16(af[mr], bfr[nc], acc[mr][nc], 0, 0, 0);
    __syncthreads();
  }

  #pragma unroll
  for (int mr = 0; mr < 4; ++mr) {
    #pragma unroll
    for (int nc = 0; nc < 4; ++nc) {
      int c = col0 + wc * 64 + nc * 16 + lr;
      int rb = row0 + wr * 64 + mr * 16 + lg * 4;
      float vv[4];
      #pragma unroll
      for (int j = 0; j < 4; ++j) {
        float t = acc[mr][nc][j] + bias[c];
        if (RES) t += res[(size_t)(rb + j) * N + c];
        if (GELU_ACT) t = 0.5f * t * (1.0f + erff(t * 0.70710678118654752f));
        vv[j] = t;
      }
      if (OMODE == 0) {
        float* out = (float*)outp;
        #pragma unroll
        for (int j = 0; j < 4; ++j) out[(size_t)(rb + j) * N + c] = vv[j];
      } else if (OMODE == 1) {
        __bf16* out = (__bf16*)outp;
        #pragma unroll
        for (int j = 0; j < 4; ++j) out[(size_t)(rb + j) * N + c] = (__bf16)vv[j];
      } else if (OMODE == 3) {
        float* out = (float*)outp;
        __bf16* out2 = (__bf16*)outp2;
        #pragma unroll
        for (int j = 0; j < 4; ++j) {
          out[(size_t)(rb + j) * N + c] = vv[j];
          out2[(size_t)(rb + j) * N + c] = (__bf16)vv[j];
        }
      } else {  // OMODE 4: fused QKV epilogue
        if (col0 < 512) {
          __bf16* out = (__bf16*)outp;
          #pragma unroll
          for (int j = 0; j < 4; ++j) out[(size_t)(rb + j) * D_ + c] = (__bf16)vv[j];
        } else if (col0 < 1024) {
          __bf16* out = (__bf16*)outp2;
          #pragma unroll
          for (int j = 0; j < 4; ++j) out[(size_t)(rb + j) * D_ + (c - 512)] = (__bf16)vv[j];
        } else {
          __bf16* out = (__bf16*)outp3;   // vt [B][D][S]
          int b = rb >> 10, s0 = rb & (S_ - 1);
          bf16x4 pk;
          #pragma unroll
          for (int j = 0; j < 4; ++j) pk[j] = (__bf16)vv[j];
          *reinterpret_cast<bf16x4*>(&out[((size_t)b * D_ + (c - 1024)) * S_ + s0]) = pk;
        }
      }
    }
  }
}

// ---------------- 64x128-tile GEMM for N=512 shapes (Wo, W2) -> 256 workgroups ----------------
template<int OMODE, bool RES>
__global__ __launch_bounds__(256)
void gemm64_kernel(const __bf16* __restrict__ A, const __bf16* __restrict__ WT,
                   const float* __restrict__ bias, const float* __restrict__ res,
                   void* __restrict__ outp, void* __restrict__ outp2,
                   int M, int N, int Kd) {
  __shared__ __bf16 As[64 * BK];
  __shared__ __bf16 Ws[BN * BK];
  int tid = threadIdx.x;
  int lane = tid & 63, w = tid >> 6;
  int wr = w >> 1, wc = w & 1;              // 2x2 waves, each 32x64
  int lr = lane & 15, lg = lane >> 4;
  int row0 = blockIdx.x * 64, col0 = blockIdx.y * BN;

  int srow = lane >> 2;
  int schunk = lane & 3;
  const __bf16* Abase = A + (size_t)(row0 + srow) * Kd + schunk * 8;
  const __bf16* Wbase = WT + (size_t)(col0 + srow) * Kd + schunk * 8;

  f32x4v acc[2][4];
  #pragma unroll
  for (int i = 0; i < 2; ++i)
    #pragma unroll
    for (int j = 0; j < 4; ++j)
      #pragma unroll
      for (int e = 0; e < 4; ++e) acc[i][j][e] = 0.0f;

  for (int k0 = 0; k0 < Kd; k0 += BK) {
    gload_lds16(Abase + (size_t)(w * 16) * Kd + k0, &As[w * 16 * BK]);
    #pragma unroll
    for (int p = 0; p < 2; ++p) {
      int r0 = p * 64 + w * 16;
      gload_lds16(Wbase + (size_t)r0 * Kd + k0, &Ws[r0 * BK]);
    }
    __syncthreads();
    bf16x8 af[2], bfr[4];
    #pragma unroll
    for (int mr = 0; mr < 2; ++mr)
      af[mr] = *reinterpret_cast<const bf16x8*>(&As[(wr * 32 + mr * 16 + lr) * BK + lg * 8]);
    #pragma unroll
    for (int nc = 0; nc < 4; ++nc)
      bfr[nc] = *reinterpret_cast<const bf16x8*>(&Ws[(wc * 64 + nc * 16 + lr) * BK + lg * 8]);
    #pragma unroll
    for (int mr = 0; mr < 2; ++mr)
      #pragma unroll
      for (int nc = 0; nc < 4; ++nc)
        acc[mr][nc] = __builtin_amdgcn_mfma_f32_16x16x32_bf16(af[mr], bfr[nc], acc[mr][nc], 0, 0, 0);
    __syncthreads();
  }

  #pragma unroll
  for (int mr = 0; mr < 2; ++mr) {
    #pragma unroll
    for (int nc = 0; nc < 4; ++nc) {
      int c = col0 + wc * 64 + nc * 16 + lr;
      int rb = row0 + wr * 32 + mr * 16 + lg * 4;
      float vv[4];
      #pragma unroll
      for (int j = 0; j < 4; ++j) {
        float t = acc[mr][nc][j] + bias[c];
        if (RES) t += res[(size_t)(rb + j) * N + c];
        vv[j] = t;
      }
      if (OMODE == 0) {
        float* out = (float*)outp;
        #pragma unroll
        for (int j = 0; j < 4; ++j) out[(size_t)(rb + j) * N + c] = vv[j];
      } else {  // OMODE 3
        float* out = (float*)outp;
        __bf16* out2 = (__bf16*)outp2;
        #pragma unroll
        for (int j = 0; j < 4; ++j) {
          out[(size_t)(rb + j) * N + c] = vv[j];
          out2[(size_t)(rb + j) * N + c] = (__bf16)vv[j];
        }
      }
    }
  }
}

// ---------------- fused attention: MFMA scores -> top-307 -> softmax -> MFMA PV ----------------
// 16 q-rows per block, 4 waves. u16 (bf16-mapped) scores: LDS 33.6 KB -> 4 blocks/CU.
__global__ __launch_bounds__(256)
void attn_kernel(const __bf16* __restrict__ qm, const __bf16* __restrict__ km,
                 const __bf16* __restrict__ vt, __bf16* __restrict__ o) {
  __shared__ unsigned short sc16[16][SRS];   // mapped u16 scores; reused as bf16 P (same cols)
  __shared__ float rs[16];
  const int q0 = blockIdx.x * 16;
  const int hh = blockIdx.y;
  const int bb = blockIdx.z;
  const int tid = threadIdx.x;
  const int lane = tid & 63, w = tid >> 6;
  const int lr = lane & 15, lg = lane >> 4;

  const __bf16* qrow = qm + ((size_t)(bb * S_ + q0 + lr)) * D_ + hh * DK_;
  bf16x8 qf0 = *reinterpret_cast<const bf16x8*>(qrow + lg * 8);
  bf16x8 qf1 = *reinterpret_cast<const bf16x8*>(qrow + 32 + lg * 8);

  // ---- phase 1: scores via MFMA; store bf16-bits monotone-mapped u16 ----
  const __bf16* kbase = km + ((size_t)bb * S_) * D_ + hh * DK_;
  #pragma unroll 4
  for (int kt = 0; kt < 16; ++kt) {
    int key0 = kt * 64 + w * 16;
    const __bf16* krow = kbase + (size_t)(key0 + lr) * D_;
    bf16x8 kf0 = *reinterpret_cast<const bf16x8*>(krow + lg * 8);
    bf16x8 kf1 = *reinterpret_cast<const bf16x8*>(krow + 32 + lg * 8);
    f32x4v d = {0.0f, 0.0f, 0.0f, 0.0f};
    d = __builtin_amdgcn_mfma_f32_16x16x32_bf16(qf0, kf0, d, 0, 0, 0);
    d = __builtin_amdgcn_mfma_f32_16x16x32_bf16(qf1, kf1, d, 0, 0, 0);
    #pragma unroll
    for (int j = 0; j < 4; ++j) {
      unsigned int u = f32_to_bf16_bits(d[j] * 0.125f);
      u = (u & 0x8000u) ? (~u & 0xFFFFu) : (u | 0x8000u);   // monotone map
      sc16[lg * 4 + j][key0 + lr] = (unsigned short)u;
    }
  }
  __syncthreads();

  // ---- phase 2: 16 threads/row; 16-bit binary search with packed-u32 counts ----
  {
    int r = tid >> 4, tc = tid & 15;
    const unsigned int* srow = reinterpret_cast<const unsigned int*>(&sc16[r][0]);
    unsigned int wv[32];   // 64 u16 values packed
    #pragma unroll
    for (int g = 0; g < 8; ++g) {
      uint4 t4 = *reinterpret_cast<const uint4*>(&srow[g * 64 + tc * 4]);
      wv[g * 4 + 0] = t4.x; wv[g * 4 + 1] = t4.y;
      wv[g * 4 + 2] = t4.z; wv[g * 4 + 3] = t4.w;
    }
    unsigned int umax = 0;
    #pragma unroll
    for (int i = 0; i < 32; ++i) {
      unsigned int a = wv[i] & 0xFFFFu, b = wv[i] >> 16;
      unsigned int mx = a > b ? a : b;
      umax = mx > umax ? mx : umax;
    }
    #pragma unroll
    for (int m = 1; m < 16; m <<= 1) {
      unsigned int other = (unsigned int)__shfl_xor((int)umax, m, 64);
      umax = other > umax ? other : umax;
    }
    unsigned int lo = 0;
    for (int bit = 15; bit >= 0; --bit) {
      unsigned int cs = (lo | (1u << bit)) << 16;
      int cnt = 0;
      #pragma unroll
      for (int i = 0; i < 32; ++i) {
        cnt += ((wv[i] << 16) >= cs) ? 1 : 0;   // lo16 >= c
        cnt += (wv[i] >= cs) ? 1 : 0;           // hi16 >= c
      }
      #pragma unroll
      for (int m = 1; m < 16; m <<= 1) cnt += __shfl_xor(cnt, m, 64);
      if (cnt >= KTOP) lo |= (1u << bit);
    }
    unsigned int um = (umax & 0x8000u) ? (umax ^ 0x8000u) : (~umax & 0xFFFFu);
    float mval = __uint_as_float(um << 16);

    __bf16* P = reinterpret_cast<__bf16*>(&sc16[r][0]);   // overlays this row's own cols
    float lsum = 0.0f;
    #pragma unroll
    for (int g = 0; g < 8; ++g) {
      bf16x8 pk;
      #pragma unroll
      for (int e = 0; e < 8; ++e) {
        unsigned int wrd = wv[g * 4 + (e >> 1)];
        unsigned int u = (e & 1) ? (wrd >> 16) : (wrd & 0xFFFFu);
        float p = 0.0f;
        if (u >= lo) {
          unsigned int ub = (u & 0x8000u) ? (u ^ 0x8000u) : (~u & 0xFFFFu);
          p = __expf(__uint_as_float(ub << 16) - mval);
        }
        pk[e] = (__bf16)p;
        lsum += (float)pk[e];
      }
      *reinterpret_cast<bf16x8*>(&P[tc * 8 + g * 128]) = pk;
    }
    #pragma unroll
    for (int m = 1; m < 16; m <<= 1) lsum += __shfl_xor(lsum, m, 64);
    if (tc == 0) rs[r] = lsum;
  }
  __syncthreads();

  // ---- phase 3: o = (P @ V) / rowsum via MFMA; V^T fragments straight from global ----
  {
    const __bf16* P0 = reinterpret_cast<const __bf16*>(&sc16[0][0]);
    const __bf16* vbase = vt + ((size_t)bb * D_ + hh * DK_ + w * 16 + lr) * S_;
    const __bf16* prow = P0 + (size_t)lr * SRS;
    f32x4v oacc = {0.0f, 0.0f, 0.0f, 0.0f};
    #pragma unroll 4
    for (int kt = 0; kt < 32; ++kt) {
      bf16x8 a = *reinterpret_cast<const bf16x8*>(prow + kt * 32 + lg * 8);
      bf16x8 b = *reinterpret_cast<const bf16x8*>(vbase + kt * 32 + lg * 8);
      oacc = __builtin_amdgcn_mfma_f32_16x16x32_bf16(a, b, oacc, 0, 0, 0);
    }
    #pragma unroll
    for (int j = 0; j < 4; ++j) {
      int qr = lg * 4 + j;
      float ov = oacc[j] / rs[qr];
      o[((size_t)(bb * S_ + q0 + qr)) * D_ + hh * DK_ + w * 16 + lr] = (__bf16)ov;
    }
  }
}

extern "C" void kernel_launch(void* const* d_in, const int* in_sizes, int n_in,
                              void* d_out, int out_size, void* d_ws, size_t ws_size,
                              hipStream_t stream) {
  (void)in_sizes; (void)n_in; (void)out_size; (void)ws_size;
  const int*   x    = (const int*)d_in[0];
  const float* tok  = (const float*)d_in[1];
  const float* pos  = (const float*)d_in[2];
  const float* Wq   = (const float*)d_in[3];
  const float* bq   = (const float*)d_in[4];
  const float* Wk   = (const float*)d_in[5];
  const float* bk   = (const float*)d_in[6];
  const float* Wv   = (const float*)d_in[7];
  const float* bv   = (const float*)d_in[8];
  const float* Wo   = (const float*)d_in[9];
  const float* bo   = (const float*)d_in[10];
  const float* g1   = (const float*)d_in[11];
  const float* be1  = (const float*)d_in[12];
  const float* g2   = (const float*)d_in[13];
  const float* be2  = (const float*)d_in[14];
  const float* W1   = (const float*)d_in[15];
  const float* b1   = (const float*)d_in[16];
  const float* Wm   = (const float*)d_in[17];
  const float* bm   = (const float*)d_in[18];
  const float* W2   = (const float*)d_in[19];
  const float* b2   = (const float*)d_in[20];
  const float* Wout = (const float*)d_in[21];
  const float* bout = (const float*)d_in[22];
  float* logits = (float*)d_out;

  const int M = B_ * S_;  // 4096
  float* ws = (float*)d_ws;
  float* h    = ws;                                   // fp32 [M][D]
  float* bqkv = h + (size_t)M * D_;                   // fp32 [L][1536]
  __bf16* y16  = (__bf16*)(bqkv + (size_t)L_ * 1536);
  __bf16* f1b  = y16  + (size_t)M * D_;
  __bf16* f2b  = f1b  + (size_t)M * DFF_;
  __bf16* qb16 = f2b  + (size_t)M * DFF_;
  __bf16* kb16 = qb16 + (size_t)M * D_;
  __bf16* vt16 = kb16 + (size_t)M * D_;               // [B][D][S]
  __bf16* ob16 = vt16 + (size_t)M * D_;
  __bf16* h16  = ob16 + (size_t)M * D_;
  __bf16* WqkvT = h16 + (size_t)M * D_;               // [l][1536][512]
  __bf16* WoT  = WqkvT + (size_t)L_ * 1536 * D_;
  __bf16* W1T  = WoT  + (size_t)L_ * D_ * D_;         // [l][DFF][D]
  __bf16* WmT  = W1T  + (size_t)L_ * D_ * DFF_;       // [l][DFF][DFF]
  __bf16* W2T  = WmT  + (size_t)L_ * DFF_ * DFF_;     // [l][D][DFF]
  __bf16* WoutT = W2T + (size_t)L_ * D_ * DFF_;       // [V][D]

  const long DD = (long)D_ * D_;
  transpose_bf16_kernel<<<dim3(D_/32,  D_/32,   L_), 256, 0, stream>>>(Wq, WqkvT,            D_, D_, DD, 1536L*D_);
  transpose_bf16_kernel<<<dim3(D_/32,  D_/32,   L_), 256, 0, stream>>>(Wk, WqkvT + 512*512,  D_, D_, DD, 1536L*D_);
  transpose_bf16_kernel<<<dim3(D_/32,  D_/32,   L_), 256, 0, stream>>>(Wv, WqkvT + 1024*512, D_, D_, DD, 1536L*D_);
  transpose_bf16_kernel<<<dim3(D_/32,  D_/32,   L_), 256, 0, stream>>>(Wo, WoT, D_, D_, DD, DD);
  transpose_bf16_kernel<<<dim3(DFF_/32, D_/32,  L_), 256, 0, stream>>>(W1, W1T, D_, DFF_, (long)D_*DFF_, (long)D_*DFF_);
  transpose_bf16_kernel<<<dim3(DFF_/32, DFF_/32,L_), 256, 0, stream>>>(Wm, WmT, DFF_, DFF_, (long)DFF_*DFF_, (long)DFF_*DFF_);
  transpose_bf16_kernel<<<dim3(D_/32,  DFF_/32, L_), 256, 0, stream>>>(W2, W2T, DFF_, D_, (long)D_*DFF_, (long)D_*DFF_);
  transpose_bf16_kernel<<<dim3(V_/32,  D_/32,   1 ), 256, 0, stream>>>(Wout, WoutT, D_, V_, (long)D_*V_, (long)D_*V_);
  concat_bias_kernel<<<(L_*1536)/256, 256, 0, stream>>>(bq, bk, bv, bqkv);

  embed_kernel<<<M, 128, 0, stream>>>(x, tok, pos, h);

  for (int l = 0; l < L_; ++l) {
    ln_kernel<<<M, 256, 0, stream>>>(h, g1 + l * D_, be1 + l * D_, y16);
    gemm_bf16_kernel<4,false,false,false><<<dim3(M/BM, 1536/BN), 256, 0, stream>>>(
        y16, WqkvT + (size_t)l * 1536 * D_, bqkv + l * 1536, nullptr,
        qb16, kb16, vt16, M, 1536, D_);
    attn_kernel<<<dim3(S_/16, H_, B_), 256, 0, stream>>>(qb16, kb16, vt16, ob16);
    gemm64_kernel<0,true><<<dim3(M/64, D_/BN), 256, 0, stream>>>(
        ob16, WoT + (size_t)l * DD, bo + l * D_, h, h, nullptr, M, D_, D_);
    ln_kernel<<<M, 256, 0, stream>>>(h, g2 + l * D_, be2 + l * D_, y16);
    gemm_bf16_kernel<1,true,false,false><<<dim3(M/BM, DFF_/BN), 256, 0, stream>>>(
        y16, W1T + (size_t)l * D_ * DFF_, b1 + l * DFF_, nullptr, f1b, nullptr, nullptr, M, DFF_, D_);
    gemm_bf16_kernel<1,true,false,false><<<dim3(M/BM, DFF_/BN), 256, 0, stream>>>(
        f1b, WmT + (size_t)l * DFF_ * DFF_, bm + l * DFF_, nullptr, f2b, nullptr, nullptr, M, DFF_, DFF_);
    gemm64_kernel<3,true><<<dim3(M/64, D_/BN), 256, 0, stream>>>(
        f2b, W2T + (size_t)l * D_ * DFF_, b2 + l * D_, h, h, h16, M, D_, DFF_);
  }
  gemm_bf16_kernel<0,false,false,true><<<dim3((M/BM) * (V_/BN)), 256, 0, stream>>>(
      h16, WoutT, bout, nullptr, logits, nullptr, nullptr, M, V_, D_);
}

// Round 7
// 1343.879 us; speedup vs baseline: 1.3016x; 1.0474x over previous
//
#include <hip/hip_runtime.h>
#include <hip/hip_bf16.h>
#include <math.h>

#define B_ 4
#define S_ 1024
#define D_ 512
#define H_ 8
#define L_ 4
#define DFF_ 2048
#define V_ 32000
#define DK_ 64
#define KTOP 307
#define SRS 1048    // score row stride in u16 elems

using bf16x8 = __attribute__((ext_vector_type(8))) __bf16;
using bf16x4 = __attribute__((ext_vector_type(4))) __bf16;
using bf16x2 = __attribute__((ext_vector_type(2))) __bf16;
using f32x4v = __attribute__((ext_vector_type(4))) float;

__device__ __forceinline__ void gload_lds16(const __bf16* g, __bf16* l) {
  __builtin_amdgcn_global_load_lds(
      (const __attribute__((address_space(1))) void*)g,
      (__attribute__((address_space(3))) void*)l, 16, 0, 0);
}

// fp32 -> bf16 bits (RNE), as low 16 of u32
__device__ __forceinline__ unsigned int f32_to_bf16_bits(float s) {
  unsigned int x = __float_as_uint(s);
  return (x + 0x7FFFu + ((x >> 16) & 1u)) >> 16;
}

// ---- st_16x32-swizzled [R][64] bf16 LDS helpers (write: linear dest, pre-swizzled src col) ----
// stage 8-row chunks: 4-wave (256 thr) version
template<int ROWS>
__device__ __forceinline__ void stage_tile4(const __bf16* src, int Kd, __bf16* lds,
                                            int w, int lane) {
  #pragma unroll
  for (int c = 0; c < ROWS / 32; ++c) {
    int rblk = (c * 4 + w) * 8;              // wave-uniform
    int row = rblk + (lane >> 3);
    int col = (lane & 7) * 8;
    int scol = col ^ ((row & 4) ? 16 : 0);   // inverse swizzle on source
    gload_lds16(src + (size_t)row * Kd + scol, lds + rblk * 64);
  }
}
// 8-wave (512 thr) version, 128-row half-tile
__device__ __forceinline__ void stage_half8(const __bf16* src, int Kd, __bf16* lds,
                                            int w, int lane) {
  #pragma unroll
  for (int c = 0; c < 2; ++c) {
    int rblk = (c * 8 + w) * 8;
    int row = rblk + (lane >> 3);
    int col = (lane & 7) * 8;
    int scol = col ^ ((row & 4) ? 16 : 0);
    gload_lds16(src + (size_t)row * Kd + scol, lds + rblk * 64);
  }
}
__device__ __forceinline__ bf16x8 lds_frag64(const __bf16* lds, int row, int colbase) {
  int col = colbase ^ ((row & 4) ? 16 : 0);
  return *reinterpret_cast<const bf16x8*>(lds + row * 64 + col);
}

// ---------------- embedding: h = tok_emb[x] + pos_emb ----------------
__global__ void embed_kernel(const int* __restrict__ x, const float* __restrict__ tok,
                             const float* __restrict__ pos, float* __restrict__ h) {
  int row = blockIdx.x;
  int t = threadIdx.x;
  int s = row & (S_ - 1);
  int token = x[row];
  const float4* t4 = reinterpret_cast<const float4*>(tok + (size_t)token * D_);
  const float4* p4 = reinterpret_cast<const float4*>(pos + (size_t)s * D_);
  float4 a = t4[t];
  float4 b = p4[t];
  a.x += b.x; a.y += b.y; a.z += b.z; a.w += b.w;
  reinterpret_cast<float4*>(h + (size_t)row * D_)[t] = a;
}

// ---------------- layernorm (one block per row, D=512), bf16 out ----------------
__global__ void ln_kernel(const float* __restrict__ xin, const float* __restrict__ g,
                          const float* __restrict__ bta, __bf16* __restrict__ y) {
  int row = blockIdx.x;
  int t = threadIdx.x;
  const float2* x2 = reinterpret_cast<const float2*>(xin + (size_t)row * D_);
  float2 v = x2[t];
  float s = v.x + v.y;
  #pragma unroll
  for (int m = 1; m < 64; m <<= 1) s += __shfl_xor(s, m, 64);
  __shared__ float red[4];
  __shared__ float red2[4];
  int wid = t >> 6, lane = t & 63;
  if (lane == 0) red[wid] = s;
  __syncthreads();
  float mu = (red[0] + red[1] + red[2] + red[3]) * (1.0f / D_);
  float dx = v.x - mu, dy = v.y - mu;
  float s2 = dx * dx + dy * dy;
  #pragma unroll
  for (int m = 1; m < 64; m <<= 1) s2 += __shfl_xor(s2, m, 64);
  if (lane == 0) red2[wid] = s2;
  __syncthreads();
  float var = (red2[0] + red2[1] + red2[2] + red2[3]) * (1.0f / D_);
  float rstd = rsqrtf(var + 1e-5f);
  float2 gg = reinterpret_cast<const float2*>(g)[t];
  float2 bb = reinterpret_cast<const float2*>(bta)[t];
  bf16x2 o2;
  o2[0] = (__bf16)(dx * rstd * gg.x + bb.x);
  o2[1] = (__bf16)(dy * rstd * gg.y + bb.y);
  *reinterpret_cast<bf16x2*>(y + (size_t)row * D_ + t * 2) = o2;
}

// ------------- transpose fp32 [Kd][N] -> bf16 [N][Kd], batched over z -------------
__global__ void transpose_bf16_kernel(const float* __restrict__ in, __bf16* __restrict__ out,
                                      int Kd, int N, long in_bstride, long out_bstride) {
  __shared__ float tile[32][33];
  const float* ib = in + (size_t)blockIdx.z * in_bstride;
  __bf16* ob = out + (size_t)blockIdx.z * out_bstride;
  int n0 = blockIdx.x * 32, k0 = blockIdx.y * 32;
  int tx = threadIdx.x & 31, ty = threadIdx.x >> 5;
  #pragma unroll
  for (int i = 0; i < 4; ++i)
    tile[ty + i * 8][tx] = ib[(size_t)(k0 + ty + i * 8) * N + n0 + tx];
  __syncthreads();
  #pragma unroll
  for (int i = 0; i < 4; ++i)
    ob[(size_t)(n0 + ty + i * 8) * Kd + k0 + tx] = (__bf16)tile[tx][ty + i * 8];
}

// ---------------- bias concat for fused QKV ----------------
__global__ void concat_bias_kernel(const float* __restrict__ bq, const float* __restrict__ bk,
                                   const float* __restrict__ bv, float* __restrict__ bqkv) {
  int i = blockIdx.x * 256 + threadIdx.x;
  int l = i / 1536, c = i - l * 1536;
  float v = (c < 512) ? bq[l * 512 + c]
          : (c < 1024) ? bk[l * 512 + c - 512]
                       : bv[l * 512 + c - 1024];
  bqkv[i] = v;
}

// ---------------- bf16 MFMA GEMM, 128x128 tile, BK=64, swizzled LDS ----------------
#define BM 128
#define BN 128
#define BK 64

template<int OMODE, bool GELU_ACT, bool RES, bool SWZ>
__global__ __launch_bounds__(256)
void gemm_bf16_kernel(const __bf16* __restrict__ A, const __bf16* __restrict__ WT,
                      const float* __restrict__ bias, const float* __restrict__ res,
                      void* __restrict__ outp, void* __restrict__ outp2, void* __restrict__ outp3,
                      int M, int N, int Kd) {
  __shared__ __bf16 As[BM * BK];
  __shared__ __bf16 Ws[BN * BK];
  int tid = threadIdx.x;
  int lane = tid & 63, w = tid >> 6;
  int wr = w >> 1, wc = w & 1;
  int lr = lane & 15, lg = lane >> 4;
  int bx, by;
  if (SWZ) {
    int lid = blockIdx.x;
    int cpx = gridDim.x >> 3;
    int swz = (lid & 7) * cpx + (lid >> 3);
    int gx = M >> 7;
    bx = swz % gx;
    by = swz / gx;
  } else {
    bx = blockIdx.x; by = blockIdx.y;
  }
  int row0 = bx * BM, col0 = by * BN;

  const __bf16* Abase = A + (size_t)row0 * Kd;
  const __bf16* Wbase = WT + (size_t)col0 * Kd;

  f32x4v acc[4][4];
  #pragma unroll
  for (int i = 0; i < 4; ++i)
    #pragma unroll
    for (int j = 0; j < 4; ++j)
      #pragma unroll
      for (int e = 0; e < 4; ++e) acc[i][j][e] = 0.0f;

  for (int k0 = 0; k0 < Kd; k0 += BK) {
    stage_tile4<128>(Abase + k0, Kd, As, w, lane);
    stage_tile4<128>(Wbase + k0, Kd, Ws, w, lane);
    __syncthreads();
    bf16x8 af[4][2], bfr[4][2];
    #pragma unroll
    for (int mr = 0; mr < 4; ++mr)
      #pragma unroll
      for (int kk = 0; kk < 2; ++kk)
        af[mr][kk] = lds_frag64(As, wr * 64 + mr * 16 + lr, kk * 32 + lg * 8);
    #pragma unroll
    for (int nc = 0; nc < 4; ++nc)
      #pragma unroll
      for (int kk = 0; kk < 2; ++kk)
        bfr[nc][kk] = lds_frag64(Ws, wc * 64 + nc * 16 + lr, kk * 32 + lg * 8);
    __builtin_amdgcn_s_setprio(1);
    #pragma unroll
    for (int mr = 0; mr < 4; ++mr)
      #pragma unroll
      for (int nc = 0; nc < 4; ++nc) {
        acc[mr][nc] = __builtin_amdgcn_mfma_f32_16x16x32_bf16(af[mr][0], bfr[nc][0], acc[mr][nc], 0, 0, 0);
        acc[mr][nc] = __builtin_amdgcn_mfma_f32_16x16x32_bf16(af[mr][1], bfr[nc][1], acc[mr][nc], 0, 0, 0);
      }
    __builtin_amdgcn_s_setprio(0);
    __syncthreads();
  }

  #pragma unroll
  for (int mr = 0; mr < 4; ++mr) {
    #pragma unroll
    for (int nc = 0; nc < 4; ++nc) {
      int c = col0 + wc * 64 + nc * 16 + lr;
      int rb = row0 + wr * 64 + mr * 16 + lg * 4;
      float vv[4];
      #pragma unroll
      for (int j = 0; j < 4; ++j) {
        float t = acc[mr][nc][j] + bias[c];
        if (RES) t += res[(size_t)(rb + j) * N + c];
        if (GELU_ACT) t = 0.5f * t * (1.0f + erff(t * 0.70710678118654752f));
        vv[j] = t;
      }
      if (OMODE == 0) {
        float* out = (float*)outp;
        #pragma unroll
        for (int j = 0; j < 4; ++j) out[(size_t)(rb + j) * N + c] = vv[j];
      } else if (OMODE == 1) {
        __bf16* out = (__bf16*)outp;
        #pragma unroll
        for (int j = 0; j < 4; ++j) out[(size_t)(rb + j) * N + c] = (__bf16)vv[j];
      } else if (OMODE == 3) {
        float* out = (float*)outp;
        __bf16* out2 = (__bf16*)outp2;
        #pragma unroll
        for (int j = 0; j < 4; ++j) {
          out[(size_t)(rb + j) * N + c] = vv[j];
          out2[(size_t)(rb + j) * N + c] = (__bf16)vv[j];
        }
      } else {  // OMODE 4: fused QKV epilogue
        if (col0 < 512) {
          __bf16* out = (__bf16*)outp;
          #pragma unroll
          for (int j = 0; j < 4; ++j) out[(size_t)(rb + j) * D_ + c] = (__bf16)vv[j];
        } else if (col0 < 1024) {
          __bf16* out = (__bf16*)outp2;
          #pragma unroll
          for (int j = 0; j < 4; ++j) out[(size_t)(rb + j) * D_ + (c - 512)] = (__bf16)vv[j];
        } else {
          __bf16* out = (__bf16*)outp3;   // vt [B][D][S]
          int b = rb >> 10, s0 = rb & (S_ - 1);
          bf16x4 pk;
          #pragma unroll
          for (int j = 0; j < 4; ++j) pk[j] = (__bf16)vv[j];
          *reinterpret_cast<bf16x4*>(&out[((size_t)b * D_ + (c - 1024)) * S_ + s0]) = pk;
        }
      }
    }
  }
}

// ---------------- 64x128-tile GEMM for N=512 shapes (Wo, W2), BK=64 ----------------
template<int OMODE, bool RES>
__global__ __launch_bounds__(256)
void gemm64_kernel(const __bf16* __restrict__ A, const __bf16* __restrict__ WT,
                   const float* __restrict__ bias, const float* __restrict__ res,
                   void* __restrict__ outp, void* __restrict__ outp2,
                   int M, int N, int Kd) {
  __shared__ __bf16 As[64 * BK];
  __shared__ __bf16 Ws[BN * BK];
  int tid = threadIdx.x;
  int lane = tid & 63, w = tid >> 6;
  int wr = w >> 1, wc = w & 1;
  int lr = lane & 15, lg = lane >> 4;
  int row0 = blockIdx.x * 64, col0 = blockIdx.y * BN;

  const __bf16* Abase = A + (size_t)row0 * Kd;
  const __bf16* Wbase = WT + (size_t)col0 * Kd;

  f32x4v acc[2][4];
  #pragma unroll
  for (int i = 0; i < 2; ++i)
    #pragma unroll
    for (int j = 0; j < 4; ++j)
      #pragma unroll
      for (int e = 0; e < 4; ++e) acc[i][j][e] = 0.0f;

  for (int k0 = 0; k0 < Kd; k0 += BK) {
    stage_tile4<64>(Abase + k0, Kd, As, w, lane);
    stage_tile4<128>(Wbase + k0, Kd, Ws, w, lane);
    __syncthreads();
    bf16x8 af[2][2], bfr[4][2];
    #pragma unroll
    for (int mr = 0; mr < 2; ++mr)
      #pragma unroll
      for (int kk = 0; kk < 2; ++kk)
        af[mr][kk] = lds_frag64(As, wr * 32 + mr * 16 + lr, kk * 32 + lg * 8);
    #pragma unroll
    for (int nc = 0; nc < 4; ++nc)
      #pragma unroll
      for (int kk = 0; kk < 2; ++kk)
        bfr[nc][kk] = lds_frag64(Ws, wc * 64 + nc * 16 + lr, kk * 32 + lg * 8);
    __builtin_amdgcn_s_setprio(1);
    #pragma unroll
    for (int mr = 0; mr < 2; ++mr)
      #pragma unroll
      for (int nc = 0; nc < 4; ++nc) {
        acc[mr][nc] = __builtin_amdgcn_mfma_f32_16x16x32_bf16(af[mr][0], bfr[nc][0], acc[mr][nc], 0, 0, 0);
        acc[mr][nc] = __builtin_amdgcn_mfma_f32_16x16x32_bf16(af[mr][1], bfr[nc][1], acc[mr][nc], 0, 0, 0);
      }
    __builtin_amdgcn_s_setprio(0);
    __syncthreads();
  }

  #pragma unroll
  for (int mr = 0; mr < 2; ++mr) {
    #pragma unroll
    for (int nc = 0; nc < 4; ++nc) {
      int c = col0 + wc * 64 + nc * 16 + lr;
      int rb = row0 + wr * 32 + mr * 16 + lg * 4;
      float vv[4];
      #pragma unroll
      for (int j = 0; j < 4; ++j) {
        float t = acc[mr][nc][j] + bias[c];
        if (RES) t += res[(size_t)(rb + j) * N + c];
        vv[j] = t;
      }
      if (OMODE == 0) {
        float* out = (float*)outp;
        #pragma unroll
        for (int j = 0; j < 4; ++j) out[(size_t)(rb + j) * N + c] = vv[j];
      } else {
        float* out = (float*)outp;
        __bf16* out2 = (__bf16*)outp2;
        #pragma unroll
        for (int j = 0; j < 4; ++j) {
          out[(size_t)(rb + j) * N + c] = vv[j];
          out2[(size_t)(rb + j) * N + c] = (__bf16)vv[j];
        }
      }
    }
  }
}

// ------- head GEMM: 256x256 tile, 8 waves, BK=64, double-buffered counted-vmcnt pipeline -------
// out fp32 = A(bf16 [M][K]) @ WT(bf16 [N][K])^T + bias.  K = 512 (8 tiles).
__global__ __launch_bounds__(512)
void gemm_head_kernel(const __bf16* __restrict__ A, const __bf16* __restrict__ WT,
                      const float* __restrict__ bias, float* __restrict__ out,
                      int M, int N, int Kd) {
  __shared__ __bf16 lds[2][2][256 * 64];   // [buf][A/B] -> 128 KB
  const int tid = threadIdx.x;
  const int lane = tid & 63, w = tid >> 6;     // 8 waves
  const int wr = w >> 2, wc = w & 3;           // 2 x 4
  const int lr = lane & 15, lg = lane >> 4;

  // bijective XCD swizzle (gridDim.x = 2000, %8 == 0)
  int lid = blockIdx.x;
  int cpx = gridDim.x >> 3;
  int swz = (lid & 7) * cpx + (lid >> 3);
  int gx = M >> 8;                             // 16
  int bx = swz % gx, by = swz / gx;
  int row0 = bx * 256, col0 = by * 256;

  const __bf16* Asrc = A + (size_t)row0 * Kd;
  const __bf16* Bsrc = WT + (size_t)col0 * Kd;

  f32x4v acc[8][4];
  #pragma unroll
  for (int i = 0; i < 8; ++i)
    #pragma unroll
    for (int j = 0; j < 4; ++j)
      #pragma unroll
      for (int e = 0; e < 4; ++e) acc[i][j][e] = 0.0f;

  const int NT = Kd / 64;   // 8
  // prologue: stage tile 0 (4 half-tiles, 8 loads/thread)
  stage_half8(Asrc,                      Kd, &lds[0][0][0],    w, lane);
  stage_half8(Asrc + (size_t)128 * Kd,   Kd, &lds[0][0][8192], w, lane);
  stage_half8(Bsrc,                      Kd, &lds[0][1][0],    w, lane);
  stage_half8(Bsrc + (size_t)128 * Kd,   Kd, &lds[0][1][8192], w, lane);

  for (int t = 0; t < NT; ++t) {
    int cur = t & 1, nxt = cur ^ 1;
    int k1 = (t + 1) * 64;
    const __bf16* Ab = &lds[cur][0][0];
    const __bf16* Bb = &lds[cur][1][0];
    bf16x8 bfr[4][2];
    #pragma unroll
    for (int p = 0; p < 4; ++p) {
      // stage one half-tile of tile t+1 (issue-early; stays in flight across phases)
      if (t < NT - 1) {
        const __bf16* s;
        __bf16* d;
        if (p == 0)      { s = Asrc + k1;                    d = &lds[nxt][0][0]; }
        else if (p == 1) { s = Asrc + (size_t)128 * Kd + k1; d = &lds[nxt][0][8192]; }
        else if (p == 2) { s = Bsrc + k1;                    d = &lds[nxt][1][0]; }
        else             { s = Bsrc + (size_t)128 * Kd + k1; d = &lds[nxt][1][8192]; }
        stage_half8(s, Kd, d, w, lane);
      }
      if (p == 0) {
        // counted wait: everything older than the 2 just-issued loads (i.e. ALL of
        // tile t's stages) is complete; barrier makes it cross-wave.
        if (t < NT - 1) asm volatile("s_waitcnt vmcnt(2)" ::: "memory");
        else            asm volatile("s_waitcnt vmcnt(0)" ::: "memory");
        __builtin_amdgcn_s_barrier();
        #pragma unroll
        for (int nn = 0; nn < 4; ++nn)
          #pragma unroll
          for (int kk = 0; kk < 2; ++kk)
            bfr[nn][kk] = lds_frag64(Bb, wc * 64 + nn * 16 + lr, kk * 32 + lg * 8);
      }
      bf16x8 af[2][2];
      #pragma unroll
      for (int mm = 0; mm < 2; ++mm)
        #pragma unroll
        for (int kk = 0; kk < 2; ++kk)
          af[mm][kk] = lds_frag64(Ab, wr * 128 + p * 32 + mm * 16 + lr, kk * 32 + lg * 8);
      asm volatile("s_waitcnt lgkmcnt(0)" ::: "memory");
      __builtin_amdgcn_sched_barrier(0);
      __builtin_amdgcn_s_setprio(1);
      #pragma unroll
      for (int mm = 0; mm < 2; ++mm)
        #pragma unroll
        for (int nn = 0; nn < 4; ++nn) {
          acc[p * 2 + mm][nn] = __builtin_amdgcn_mfma_f32_16x16x32_bf16(af[mm][0], bfr[nn][0], acc[p * 2 + mm][nn], 0, 0, 0);
          acc[p * 2 + mm][nn] = __builtin_amdgcn_mfma_f32_16x16x32_bf16(af[mm][1], bfr[nn][1], acc[p * 2 + mm][nn], 0, 0, 0);
        }
      __builtin_amdgcn_s_setprio(0);
    }
    // tile end: all waves done reading cur before next tile's stages overwrite it
    __builtin_amdgcn_s_barrier();
  }

  #pragma unroll
  for (int mg = 0; mg < 8; ++mg) {
    #pragma unroll
    for (int nn = 0; nn < 4; ++nn) {
      int c = col0 + wc * 64 + nn * 16 + lr;
      int rb = row0 + wr * 128 + mg * 16 + lg * 4;
      float b = bias[c];
      #pragma unroll
      for (int j = 0; j < 4; ++j)
        out[(size_t)(rb + j) * N + c] = acc[mg][nn][j] + b;
    }
  }
}

// ---------------- fused attention: MFMA scores -> top-307 -> softmax -> MFMA PV ----------------
__global__ __launch_bounds__(256)
void attn_kernel(const __bf16* __restrict__ qm, const __bf16* __restrict__ km,
                 const __bf16* __restrict__ vt, __bf16* __restrict__ o) {
  __shared__ unsigned short sc16[16][SRS];
  __shared__ float rs[16];
  const int q0 = blockIdx.x * 16;
  const int hh = blockIdx.y;
  const int bb = blockIdx.z;
  const int tid = threadIdx.x;
  const int lane = tid & 63, w = tid >> 6;
  const int lr = lane & 15, lg = lane >> 4;

  const __bf16* qrow = qm + ((size_t)(bb * S_ + q0 + lr)) * D_ + hh * DK_;
  bf16x8 qf0 = *reinterpret_cast<const bf16x8*>(qrow + lg * 8);
  bf16x8 qf1 = *reinterpret_cast<const bf16x8*>(qrow + 32 + lg * 8);

  const __bf16* kbase = km + ((size_t)bb * S_) * D_ + hh * DK_;
  #pragma unroll 4
  for (int kt = 0; kt < 16; ++kt) {
    int key0 = kt * 64 + w * 16;
    const __bf16* krow = kbase + (size_t)(key0 + lr) * D_;
    bf16x8 kf0 = *reinterpret_cast<const bf16x8*>(krow + lg * 8);
    bf16x8 kf1 = *reinterpret_cast<const bf16x8*>(krow + 32 + lg * 8);
    f32x4v d = {0.0f, 0.0f, 0.0f, 0.0f};
    __builtin_amdgcn_s_setprio(1);
    d = __builtin_amdgcn_mfma_f32_16x16x32_bf16(qf0, kf0, d, 0, 0, 0);
    d = __builtin_amdgcn_mfma_f32_16x16x32_bf16(qf1, kf1, d, 0, 0, 0);
    __builtin_amdgcn_s_setprio(0);
    #pragma unroll
    for (int j = 0; j < 4; ++j) {
      unsigned int u = f32_to_bf16_bits(d[j] * 0.125f);
      u = (u & 0x8000u) ? (~u & 0xFFFFu) : (u | 0x8000u);
      sc16[lg * 4 + j][key0 + lr] = (unsigned short)u;
    }
  }
  __syncthreads();

  {
    int r = tid >> 4, tc = tid & 15;
    const unsigned int* srow = reinterpret_cast<const unsigned int*>(&sc16[r][0]);
    unsigned int wv[32];
    #pragma unroll
    for (int g = 0; g < 8; ++g) {
      uint4 t4 = *reinterpret_cast<const uint4*>(&srow[g * 64 + tc * 4]);
      wv[g * 4 + 0] = t4.x; wv[g * 4 + 1] = t4.y;
      wv[g * 4 + 2] = t4.z; wv[g * 4 + 3] = t4.w;
    }
    unsigned int umax = 0;
    #pragma unroll
    for (int i = 0; i < 32; ++i) {
      unsigned int a = wv[i] & 0xFFFFu, b = wv[i] >> 16;
      unsigned int mx = a > b ? a : b;
      umax = mx > umax ? mx : umax;
    }
    #pragma unroll
    for (int m = 1; m < 16; m <<= 1) {
      unsigned int other = (unsigned int)__shfl_xor((int)umax, m, 64);
      umax = other > umax ? other : umax;
    }
    unsigned int lo = 0;
    for (int bit = 15; bit >= 0; --bit) {
      unsigned int cs = (lo | (1u << bit)) << 16;
      int cnt = 0;
      #pragma unroll
      for (int i = 0; i < 32; ++i) {
        cnt += ((wv[i] << 16) >= cs) ? 1 : 0;
        cnt += (wv[i] >= cs) ? 1 : 0;
      }
      #pragma unroll
      for (int m = 1; m < 16; m <<= 1) cnt += __shfl_xor(cnt, m, 64);
      if (cnt >= KTOP) lo |= (1u << bit);
    }
    unsigned int um = (umax & 0x8000u) ? (umax ^ 0x8000u) : (~umax & 0xFFFFu);
    float mval = __uint_as_float(um << 16);

    __bf16* P = reinterpret_cast<__bf16*>(&sc16[r][0]);
    float lsum = 0.0f;
    #pragma unroll
    for (int g = 0; g < 8; ++g) {
      bf16x8 pk;
      #pragma unroll
      for (int e = 0; e < 8; ++e) {
        unsigned int wrd = wv[g * 4 + (e >> 1)];
        unsigned int u = (e & 1) ? (wrd >> 16) : (wrd & 0xFFFFu);
        float p = 0.0f;
        if (u >= lo) {
          unsigned int ub = (u & 0x8000u) ? (u ^ 0x8000u) : (~u & 0xFFFFu);
          p = __expf(__uint_as_float(ub << 16) - mval);
        }
        pk[e] = (__bf16)p;
        lsum += (float)pk[e];
      }
      *reinterpret_cast<bf16x8*>(&P[tc * 8 + g * 128]) = pk;
    }
    #pragma unroll
    for (int m = 1; m < 16; m <<= 1) lsum += __shfl_xor(lsum, m, 64);
    if (tc == 0) rs[r] = lsum;
  }
  __syncthreads();

  {
    const __bf16* P0 = reinterpret_cast<const __bf16*>(&sc16[0][0]);
    const __bf16* vbase = vt + ((size_t)bb * D_ + hh * DK_ + w * 16 + lr) * S_;
    const __bf16* prow = P0 + (size_t)lr * SRS;
    f32x4v oacc = {0.0f, 0.0f, 0.0f, 0.0f};
    #pragma unroll 4
    for (int kt = 0; kt < 32; ++kt) {
      bf16x8 a = *reinterpret_cast<const bf16x8*>(prow + kt * 32 + lg * 8);
      bf16x8 b = *reinterpret_cast<const bf16x8*>(vbase + kt * 32 + lg * 8);
      __builtin_amdgcn_s_setprio(1);
      oacc = __builtin_amdgcn_mfma_f32_16x16x32_bf16(a, b, oacc, 0, 0, 0);
      __builtin_amdgcn_s_setprio(0);
    }
    #pragma unroll
    for (int j = 0; j < 4; ++j) {
      int qr = lg * 4 + j;
      float ov = oacc[j] / rs[qr];
      o[((size_t)(bb * S_ + q0 + qr)) * D_ + hh * DK_ + w * 16 + lr] = (__bf16)ov;
    }
  }
}

extern "C" void kernel_launch(void* const* d_in, const int* in_sizes, int n_in,
                              void* d_out, int out_size, void* d_ws, size_t ws_size,
                              hipStream_t stream) {
  (void)in_sizes; (void)n_in; (void)out_size; (void)ws_size;
  const int*   x    = (const int*)d_in[0];
  const float* tok  = (const float*)d_in[1];
  const float* pos  = (const float*)d_in[2];
  const float* Wq   = (const float*)d_in[3];
  const float* bq   = (const float*)d_in[4];
  const float* Wk   = (const float*)d_in[5];
  const float* bk   = (const float*)d_in[6];
  const float* Wv   = (const float*)d_in[7];
  const float* bv   = (const float*)d_in[8];
  const float* Wo   = (const float*)d_in[9];
  const float* bo   = (const float*)d_in[10];
  const float* g1   = (const float*)d_in[11];
  const float* be1  = (const float*)d_in[12];
  const float* g2   = (const float*)d_in[13];
  const float* be2  = (const float*)d_in[14];
  const float* W1   = (const float*)d_in[15];
  const float* b1   = (const float*)d_in[16];
  const float* Wm   = (const float*)d_in[17];
  const float* bm   = (const float*)d_in[18];
  const float* W2   = (const float*)d_in[19];
  const float* b2   = (const float*)d_in[20];
  const float* Wout = (const float*)d_in[21];
  const float* bout = (const float*)d_in[22];
  float* logits = (float*)d_out;

  const int M = B_ * S_;  // 4096
  float* ws = (float*)d_ws;
  float* h    = ws;
  float* bqkv = h + (size_t)M * D_;
  __bf16* y16  = (__bf16*)(bqkv + (size_t)L_ * 1536);
  __bf16* f1b  = y16  + (size_t)M * D_;
  __bf16* f2b  = f1b  + (size_t)M * DFF_;
  __bf16* qb16 = f2b  + (size_t)M * DFF_;
  __bf16* kb16 = qb16 + (size_t)M * D_;
  __bf16* vt16 = kb16 + (size_t)M * D_;
  __bf16* ob16 = vt16 + (size_t)M * D_;
  __bf16* h16  = ob16 + (size_t)M * D_;
  __bf16* WqkvT = h16 + (size_t)M * D_;
  __bf16* WoT  = WqkvT + (size_t)L_ * 1536 * D_;
  __bf16* W1T  = WoT  + (size_t)L_ * D_ * D_;
  __bf16* WmT  = W1T  + (size_t)L_ * D_ * DFF_;
  __bf16* W2T  = WmT  + (size_t)L_ * DFF_ * DFF_;
  __bf16* WoutT = W2T + (size_t)L_ * D_ * DFF_;

  const long DD = (long)D_ * D_;
  transpose_bf16_kernel<<<dim3(D_/32,  D_/32,   L_), 256, 0, stream>>>(Wq, WqkvT,            D_, D_, DD, 1536L*D_);
  transpose_bf16_kernel<<<dim3(D_/32,  D_/32,   L_), 256, 0, stream>>>(Wk, WqkvT + 512*512,  D_, D_, DD, 1536L*D_);
  transpose_bf16_kernel<<<dim3(D_/32,  D_/32,   L_), 256, 0, stream>>>(Wv, WqkvT + 1024*512, D_, D_, DD, 1536L*D_);
  transpose_bf16_kernel<<<dim3(D_/32,  D_/32,   L_), 256, 0, stream>>>(Wo, WoT, D_, D_, DD, DD);
  transpose_bf16_kernel<<<dim3(DFF_/32, D_/32,  L_), 256, 0, stream>>>(W1, W1T, D_, DFF_, (long)D_*DFF_, (long)D_*DFF_);
  transpose_bf16_kernel<<<dim3(DFF_/32, DFF_/32,L_), 256, 0, stream>>>(Wm, WmT, DFF_, DFF_, (long)DFF_*DFF_, (long)DFF_*DFF_);
  transpose_bf16_kernel<<<dim3(D_/32,  DFF_/32, L_), 256, 0, stream>>>(W2, W2T, DFF_, D_, (long)D_*DFF_, (long)D_*DFF_);
  transpose_bf16_kernel<<<dim3(V_/32,  D_/32,   1 ), 256, 0, stream>>>(Wout, WoutT, D_, V_, (long)D_*V_, (long)D_*V_);
  concat_bias_kernel<<<(L_*1536)/256, 256, 0, stream>>>(bq, bk, bv, bqkv);

  embed_kernel<<<M, 128, 0, stream>>>(x, tok, pos, h);

  for (int l = 0; l < L_; ++l) {
    ln_kernel<<<M, 256, 0, stream>>>(h, g1 + l * D_, be1 + l * D_, y16);
    gemm_bf16_kernel<4,false,false,true><<<dim3((M/BM) * (1536/BN)), 256, 0, stream>>>(
        y16, WqkvT + (size_t)l * 1536 * D_, bqkv + l * 1536, nullptr,
        qb16, kb16, vt16, M, 1536, D_);
    attn_kernel<<<dim3(S_/16, H_, B_), 256, 0, stream>>>(qb16, kb16, vt16, ob16);
    gemm64_kernel<0,true><<<dim3(M/64, D_/BN), 256, 0, stream>>>(
        ob16, WoT + (size_t)l * DD, bo + l * D_, h, h, nullptr, M, D_, D_);
    ln_kernel<<<M, 256, 0, stream>>>(h, g2 + l * D_, be2 + l * D_, y16);
    gemm_bf16_kernel<1,true,false,true><<<dim3((M/BM) * (DFF_/BN)), 256, 0, stream>>>(
        y16, W1T + (size_t)l * D_ * DFF_, b1 + l * DFF_, nullptr, f1b, nullptr, nullptr, M, DFF_, D_);
    gemm_bf16_kernel<1,true,false,true><<<dim3((M/BM) * (DFF_/BN)), 256, 0, stream>>>(
        f1b, WmT + (size_t)l * DFF_ * DFF_, bm + l * DFF_, nullptr, f2b, nullptr, nullptr, M, DFF_, DFF_);
    gemm64_kernel<3,true><<<dim3(M/64, D_/BN), 256, 0, stream>>>(
        f2b, W2T + (size_t)l * D_ * DFF_, b2 + l * D_, h, h, h16, M, D_, DFF_);
  }
  gemm_head_kernel<<<dim3((M/256) * (V_/256)), 512, 0, stream>>>(
      h16, WoutT, bout, logits, M, V_, D_);
}

// Round 8
// 1280.074 us; speedup vs baseline: 1.3665x; 1.0498x over previous
//
#include <hip/hip_runtime.h>
#include <hip/hip_bf16.h>
#include <math.h>

#define B_ 4
#define S_ 1024
#define D_ 512
#define H_ 8
#define L_ 4
#define DFF_ 2048
#define V_ 32000
#define DK_ 64
#define KTOP 307
#define SRS 1048    // score row stride in u16 elems

using bf16x8 = __attribute__((ext_vector_type(8))) __bf16;
using bf16x4 = __attribute__((ext_vector_type(4))) __bf16;
using bf16x2 = __attribute__((ext_vector_type(2))) __bf16;
using f32x4v = __attribute__((ext_vector_type(4))) float;

__device__ __forceinline__ void gload_lds16(const __bf16* g, __bf16* l) {
  __builtin_amdgcn_global_load_lds(
      (const __attribute__((address_space(1))) void*)g,
      (__attribute__((address_space(3))) void*)l, 16, 0, 0);
}

// fp32 -> bf16 bits (RNE), as low 16 of u32
__device__ __forceinline__ unsigned int f32_to_bf16_bits(float s) {
  unsigned int x = __float_as_uint(s);
  return (x + 0x7FFFu + ((x >> 16) & 1u)) >> 16;
}

// ---- DPP 16-lane reductions (row teams == DPP rows: lanes 0-15,16-31,...) ----
__device__ __forceinline__ int red16i(int x) {
  x += __builtin_amdgcn_update_dpp(0, x, 0xB1, 0xF, 0xF, true);   // xor1 (quad_perm 1,0,3,2)
  x += __builtin_amdgcn_update_dpp(0, x, 0x4E, 0xF, 0xF, true);   // xor2 (quad_perm 2,3,0,1)
  x += __builtin_amdgcn_update_dpp(0, x, 0x141, 0xF, 0xF, true);  // xor4 (row_half_mirror)
  x += __builtin_amdgcn_update_dpp(0, x, 0x140, 0xF, 0xF, true);  // xor8 (row_mirror)
  return x;
}
__device__ __forceinline__ unsigned int red16umax(unsigned int x) {
  unsigned int t;
  t = (unsigned int)__builtin_amdgcn_update_dpp(0, (int)x, 0xB1, 0xF, 0xF, true);  x = t > x ? t : x;
  t = (unsigned int)__builtin_amdgcn_update_dpp(0, (int)x, 0x4E, 0xF, 0xF, true);  x = t > x ? t : x;
  t = (unsigned int)__builtin_amdgcn_update_dpp(0, (int)x, 0x141, 0xF, 0xF, true); x = t > x ? t : x;
  t = (unsigned int)__builtin_amdgcn_update_dpp(0, (int)x, 0x140, 0xF, 0xF, true); x = t > x ? t : x;
  return x;
}
__device__ __forceinline__ float red16f(float x) {
  x += __int_as_float(__builtin_amdgcn_update_dpp(0, __float_as_int(x), 0xB1, 0xF, 0xF, true));
  x += __int_as_float(__builtin_amdgcn_update_dpp(0, __float_as_int(x), 0x4E, 0xF, 0xF, true));
  x += __int_as_float(__builtin_amdgcn_update_dpp(0, __float_as_int(x), 0x141, 0xF, 0xF, true));
  x += __int_as_float(__builtin_amdgcn_update_dpp(0, __float_as_int(x), 0x140, 0xF, 0xF, true));
  return x;
}
__device__ __forceinline__ float red64f(float x) {
  x = red16f(x);
  x += __shfl_xor(x, 16, 64);
  x += __shfl_xor(x, 32, 64);
  return x;
}

// ---- st_16x32-swizzled [R][64] bf16 LDS helpers; full 3-bit XOR: (row&7)<<3 elements ----
template<int ROWS>
__device__ __forceinline__ void stage_tile4(const __bf16* src, int Kd, __bf16* lds,
                                            int w, int lane) {
  #pragma unroll
  for (int c = 0; c < ROWS / 32; ++c) {
    int rblk = (c * 4 + w) * 8;              // wave-uniform
    int row = rblk + (lane >> 3);
    int col = (lane & 7) * 8;
    int scol = col ^ ((row & 7) << 3);       // inverse swizzle on source
    gload_lds16(src + (size_t)row * Kd + scol, lds + rblk * 64);
  }
}
__device__ __forceinline__ void stage_half8(const __bf16* src, int Kd, __bf16* lds,
                                            int w, int lane) {
  #pragma unroll
  for (int c = 0; c < 2; ++c) {
    int rblk = (c * 8 + w) * 8;
    int row = rblk + (lane >> 3);
    int col = (lane & 7) * 8;
    int scol = col ^ ((row & 7) << 3);
    gload_lds16(src + (size_t)row * Kd + scol, lds + rblk * 64);
  }
}
__device__ __forceinline__ bf16x8 lds_frag64(const __bf16* lds, int row, int colbase) {
  int col = colbase ^ ((row & 7) << 3);
  return *reinterpret_cast<const bf16x8*>(lds + row * 64 + col);
}

// ---------------- embedding: h = tok_emb[x] + pos_emb ----------------
__global__ void embed_kernel(const int* __restrict__ x, const float* __restrict__ tok,
                             const float* __restrict__ pos, float* __restrict__ h) {
  int row = blockIdx.x;
  int t = threadIdx.x;
  int s = row & (S_ - 1);
  int token = x[row];
  const float4* t4 = reinterpret_cast<const float4*>(tok + (size_t)token * D_);
  const float4* p4 = reinterpret_cast<const float4*>(pos + (size_t)s * D_);
  float4 a = t4[t];
  float4 b = p4[t];
  a.x += b.x; a.y += b.y; a.z += b.z; a.w += b.w;
  reinterpret_cast<float4*>(h + (size_t)row * D_)[t] = a;
}

// ---------------- layernorm (one block per row, D=512), bf16 out ----------------
__global__ void ln_kernel(const float* __restrict__ xin, const float* __restrict__ g,
                          const float* __restrict__ bta, __bf16* __restrict__ y) {
  int row = blockIdx.x;
  int t = threadIdx.x;
  const float2* x2 = reinterpret_cast<const float2*>(xin + (size_t)row * D_);
  float2 v = x2[t];
  float s = v.x + v.y;
  float q = v.x * v.x + v.y * v.y;
  s = red64f(s);
  q = red64f(q);
  __shared__ float red[4];
  __shared__ float red2[4];
  int wid = t >> 6, lane = t & 63;
  if (lane == 0) { red[wid] = s; red2[wid] = q; }
  __syncthreads();
  float mu = (red[0] + red[1] + red[2] + red[3]) * (1.0f / D_);
  float ex2 = (red2[0] + red2[1] + red2[2] + red2[3]) * (1.0f / D_);
  float var = ex2 - mu * mu;
  float rstd = rsqrtf(var + 1e-5f);
  float2 gg = reinterpret_cast<const float2*>(g)[t];
  float2 bb = reinterpret_cast<const float2*>(bta)[t];
  bf16x2 o2;
  o2[0] = (__bf16)((v.x - mu) * rstd * gg.x + bb.x);
  o2[1] = (__bf16)((v.y - mu) * rstd * gg.y + bb.y);
  *reinterpret_cast<bf16x2*>(y + (size_t)row * D_ + t * 2) = o2;
}

// ------------- transpose fp32 [Kd][N] -> bf16 [N][Kd], batched over z -------------
__global__ void transpose_bf16_kernel(const float* __restrict__ in, __bf16* __restrict__ out,
                                      int Kd, int N, long in_bstride, long out_bstride) {
  __shared__ float tile[32][33];
  const float* ib = in + (size_t)blockIdx.z * in_bstride;
  __bf16* ob = out + (size_t)blockIdx.z * out_bstride;
  int n0 = blockIdx.x * 32, k0 = blockIdx.y * 32;
  int tx = threadIdx.x & 31, ty = threadIdx.x >> 5;
  #pragma unroll
  for (int i = 0; i < 4; ++i)
    tile[ty + i * 8][tx] = ib[(size_t)(k0 + ty + i * 8) * N + n0 + tx];
  __syncthreads();
  #pragma unroll
  for (int i = 0; i < 4; ++i)
    ob[(size_t)(n0 + ty + i * 8) * Kd + k0 + tx] = (__bf16)tile[tx][ty + i * 8];
}

// ---------------- bias concat for fused QKV ----------------
__global__ void concat_bias_kernel(const float* __restrict__ bq, const float* __restrict__ bk,
                                   const float* __restrict__ bv, float* __restrict__ bqkv) {
  int i = blockIdx.x * 256 + threadIdx.x;
  int l = i / 1536, c = i - l * 1536;
  float v = (c < 512) ? bq[l * 512 + c]
          : (c < 1024) ? bk[l * 512 + c - 512]
                       : bv[l * 512 + c - 1024];
  bqkv[i] = v;
}

// ---------------- bf16 MFMA GEMM, 128x128 tile, BK=64, swizzled LDS ----------------
#define BM 128
#define BN 128
#define BK 64

template<int OMODE, bool GELU_ACT, bool RES, bool SWZ>
__global__ __launch_bounds__(256)
void gemm_bf16_kernel(const __bf16* __restrict__ A, const __bf16* __restrict__ WT,
                      const float* __restrict__ bias, const float* __restrict__ res,
                      void* __restrict__ outp, void* __restrict__ outp2, void* __restrict__ outp3,
                      int M, int N, int Kd) {
  __shared__ __bf16 As[BM * BK];
  __shared__ __bf16 Ws[BN * BK];
  int tid = threadIdx.x;
  int lane = tid & 63, w = tid >> 6;
  int wr = w >> 1, wc = w & 1;
  int lr = lane & 15, lg = lane >> 4;
  int bx, by;
  if (SWZ) {
    int lid = blockIdx.x;
    int cpx = gridDim.x >> 3;
    int swz = (lid & 7) * cpx + (lid >> 3);
    int gx = M >> 7;
    bx = swz % gx;
    by = swz / gx;
  } else {
    bx = blockIdx.x; by = blockIdx.y;
  }
  int row0 = bx * BM, col0 = by * BN;

  const __bf16* Abase = A + (size_t)row0 * Kd;
  const __bf16* Wbase = WT + (size_t)col0 * Kd;

  f32x4v acc[4][4];
  #pragma unroll
  for (int i = 0; i < 4; ++i)
    #pragma unroll
    for (int j = 0; j < 4; ++j)
      #pragma unroll
      for (int e = 0; e < 4; ++e) acc[i][j][e] = 0.0f;

  for (int k0 = 0; k0 < Kd; k0 += BK) {
    stage_tile4<128>(Abase + k0, Kd, As, w, lane);
    stage_tile4<128>(Wbase + k0, Kd, Ws, w, lane);
    __syncthreads();
    bf16x8 af[4][2], bfr[4][2];
    #pragma unroll
    for (int mr = 0; mr < 4; ++mr)
      #pragma unroll
      for (int kk = 0; kk < 2; ++kk)
        af[mr][kk] = lds_frag64(As, wr * 64 + mr * 16 + lr, kk * 32 + lg * 8);
    #pragma unroll
    for (int nc = 0; nc < 4; ++nc)
      #pragma unroll
      for (int kk = 0; kk < 2; ++kk)
        bfr[nc][kk] = lds_frag64(Ws, wc * 64 + nc * 16 + lr, kk * 32 + lg * 8);
    __builtin_amdgcn_s_setprio(1);
    #pragma unroll
    for (int mr = 0; mr < 4; ++mr)
      #pragma unroll
      for (int nc = 0; nc < 4; ++nc) {
        acc[mr][nc] = __builtin_amdgcn_mfma_f32_16x16x32_bf16(af[mr][0], bfr[nc][0], acc[mr][nc], 0, 0, 0);
        acc[mr][nc] = __builtin_amdgcn_mfma_f32_16x16x32_bf16(af[mr][1], bfr[nc][1], acc[mr][nc], 0, 0, 0);
      }
    __builtin_amdgcn_s_setprio(0);
    __syncthreads();
  }

  #pragma unroll
  for (int mr = 0; mr < 4; ++mr) {
    #pragma unroll
    for (int nc = 0; nc < 4; ++nc) {
      int c = col0 + wc * 64 + nc * 16 + lr;
      int rb = row0 + wr * 64 + mr * 16 + lg * 4;
      float vv[4];
      #pragma unroll
      for (int j = 0; j < 4; ++j) {
        float t = acc[mr][nc][j] + bias[c];
        if (RES) t += res[(size_t)(rb + j) * N + c];
        if (GELU_ACT) t = 0.5f * t * (1.0f + erff(t * 0.70710678118654752f));
        vv[j] = t;
      }
      if (OMODE == 0) {
        float* out = (float*)outp;
        #pragma unroll
        for (int j = 0; j < 4; ++j) out[(size_t)(rb + j) * N + c] = vv[j];
      } else if (OMODE == 1) {
        __bf16* out = (__bf16*)outp;
        #pragma unroll
        for (int j = 0; j < 4; ++j) out[(size_t)(rb + j) * N + c] = (__bf16)vv[j];
      } else if (OMODE == 3) {
        float* out = (float*)outp;
        __bf16* out2 = (__bf16*)outp2;
        #pragma unroll
        for (int j = 0; j < 4; ++j) {
          out[(size_t)(rb + j) * N + c] = vv[j];
          out2[(size_t)(rb + j) * N + c] = (__bf16)vv[j];
        }
      } else {  // OMODE 4: fused QKV epilogue
        if (col0 < 512) {
          __bf16* out = (__bf16*)outp;
          #pragma unroll
          for (int j = 0; j < 4; ++j) out[(size_t)(rb + j) * D_ + c] = (__bf16)vv[j];
        } else if (col0 < 1024) {
          __bf16* out = (__bf16*)outp2;
          #pragma unroll
          for (int j = 0; j < 4; ++j) out[(size_t)(rb + j) * D_ + (c - 512)] = (__bf16)vv[j];
        } else {
          __bf16* out = (__bf16*)outp3;   // vt [B][D][S]
          int b = rb >> 10, s0 = rb & (S_ - 1);
          bf16x4 pk;
          #pragma unroll
          for (int j = 0; j < 4; ++j) pk[j] = (__bf16)vv[j];
          *reinterpret_cast<bf16x4*>(&out[((size_t)b * D_ + (c - 1024)) * S_ + s0]) = pk;
        }
      }
    }
  }
}

// ---------------- 64x128-tile GEMM for N=512 shapes (Wo, W2), BK=64 ----------------
template<int OMODE, bool RES>
__global__ __launch_bounds__(256)
void gemm64_kernel(const __bf16* __restrict__ A, const __bf16* __restrict__ WT,
                   const float* __restrict__ bias, const float* __restrict__ res,
                   void* __restrict__ outp, void* __restrict__ outp2,
                   int M, int N, int Kd) {
  __shared__ __bf16 As[64 * BK];
  __shared__ __bf16 Ws[BN * BK];
  int tid = threadIdx.x;
  int lane = tid & 63, w = tid >> 6;
  int wr = w >> 1, wc = w & 1;
  int lr = lane & 15, lg = lane >> 4;
  int row0 = blockIdx.x * 64, col0 = blockIdx.y * BN;

  const __bf16* Abase = A + (size_t)row0 * Kd;
  const __bf16* Wbase = WT + (size_t)col0 * Kd;

  f32x4v acc[2][4];
  #pragma unroll
  for (int i = 0; i < 2; ++i)
    #pragma unroll
    for (int j = 0; j < 4; ++j)
      #pragma unroll
      for (int e = 0; e < 4; ++e) acc[i][j][e] = 0.0f;

  for (int k0 = 0; k0 < Kd; k0 += BK) {
    stage_tile4<64>(Abase + k0, Kd, As, w, lane);
    stage_tile4<128>(Wbase + k0, Kd, Ws, w, lane);
    __syncthreads();
    bf16x8 af[2][2], bfr[4][2];
    #pragma unroll
    for (int mr = 0; mr < 2; ++mr)
      #pragma unroll
      for (int kk = 0; kk < 2; ++kk)
        af[mr][kk] = lds_frag64(As, wr * 32 + mr * 16 + lr, kk * 32 + lg * 8);
    #pragma unroll
    for (int nc = 0; nc < 4; ++nc)
      #pragma unroll
      for (int kk = 0; kk < 2; ++kk)
        bfr[nc][kk] = lds_frag64(Ws, wc * 64 + nc * 16 + lr, kk * 32 + lg * 8);
    __builtin_amdgcn_s_setprio(1);
    #pragma unroll
    for (int mr = 0; mr < 2; ++mr)
      #pragma unroll
      for (int nc = 0; nc < 4; ++nc) {
        acc[mr][nc] = __builtin_amdgcn_mfma_f32_16x16x32_bf16(af[mr][0], bfr[nc][0], acc[mr][nc], 0, 0, 0);
        acc[mr][nc] = __builtin_amdgcn_mfma_f32_16x16x32_bf16(af[mr][1], bfr[nc][1], acc[mr][nc], 0, 0, 0);
      }
    __builtin_amdgcn_s_setprio(0);
    __syncthreads();
  }

  #pragma unroll
  for (int mr = 0; mr < 2; ++mr) {
    #pragma unroll
    for (int nc = 0; nc < 4; ++nc) {
      int c = col0 + wc * 64 + nc * 16 + lr;
      int rb = row0 + wr * 32 + mr * 16 + lg * 4;
      float vv[4];
      #pragma unroll
      for (int j = 0; j < 4; ++j) {
        float t = acc[mr][nc][j] + bias[c];
        if (RES) t += res[(size_t)(rb + j) * N + c];
        vv[j] = t;
      }
      if (OMODE == 0) {
        float* out = (float*)outp;
        #pragma unroll
        for (int j = 0; j < 4; ++j) out[(size_t)(rb + j) * N + c] = vv[j];
      } else {
        float* out = (float*)outp;
        __bf16* out2 = (__bf16*)outp2;
        #pragma unroll
        for (int j = 0; j < 4; ++j) {
          out[(size_t)(rb + j) * N + c] = vv[j];
          out2[(size_t)(rb + j) * N + c] = (__bf16)vv[j];
        }
      }
    }
  }
}

// ------- head GEMM: 256x256 tile, 8 waves, BK=64, double-buffered counted-vmcnt pipeline -------
__global__ __launch_bounds__(512)
void gemm_head_kernel(const __bf16* __restrict__ A, const __bf16* __restrict__ WT,
                      const float* __restrict__ bias, float* __restrict__ out,
                      int M, int N, int Kd) {
  __shared__ __bf16 lds[2][2][256 * 64];   // [buf][A/B] -> 128 KB
  const int tid = threadIdx.x;
  const int lane = tid & 63, w = tid >> 6;     // 8 waves
  const int wr = w >> 2, wc = w & 3;           // 2 x 4
  const int lr = lane & 15, lg = lane >> 4;

  int lid = blockIdx.x;
  int cpx = gridDim.x >> 3;
  int swz = (lid & 7) * cpx + (lid >> 3);
  int gx = M >> 8;                             // 16
  int bx = swz % gx, by = swz / gx;
  int row0 = bx * 256, col0 = by * 256;

  const __bf16* Asrc = A + (size_t)row0 * Kd;
  const __bf16* Bsrc = WT + (size_t)col0 * Kd;

  f32x4v acc[8][4];
  #pragma unroll
  for (int i = 0; i < 8; ++i)
    #pragma unroll
    for (int j = 0; j < 4; ++j)
      #pragma unroll
      for (int e = 0; e < 4; ++e) acc[i][j][e] = 0.0f;

  const int NT = Kd / 64;   // 8
  stage_half8(Asrc,                      Kd, &lds[0][0][0],    w, lane);
  stage_half8(Asrc + (size_t)128 * Kd,   Kd, &lds[0][0][8192], w, lane);
  stage_half8(Bsrc,                      Kd, &lds[0][1][0],    w, lane);
  stage_half8(Bsrc + (size_t)128 * Kd,   Kd, &lds[0][1][8192], w, lane);

  for (int t = 0; t < NT; ++t) {
    int cur = t & 1, nxt = cur ^ 1;
    int k1 = (t + 1) * 64;
    const __bf16* Ab = &lds[cur][0][0];
    const __bf16* Bb = &lds[cur][1][0];
    bf16x8 bfr[4][2];
    #pragma unroll
    for (int p = 0; p < 4; ++p) {
      if (t < NT - 1) {
        const __bf16* s;
        __bf16* d;
        if (p == 0)      { s = Asrc + k1;                    d = &lds[nxt][0][0]; }
        else if (p == 1) { s = Asrc + (size_t)128 * Kd + k1; d = &lds[nxt][0][8192]; }
        else if (p == 2) { s = Bsrc + k1;                    d = &lds[nxt][1][0]; }
        else             { s = Bsrc + (size_t)128 * Kd + k1; d = &lds[nxt][1][8192]; }
        stage_half8(s, Kd, d, w, lane);
      }
      if (p == 0) {
        if (t < NT - 1) asm volatile("s_waitcnt vmcnt(2)" ::: "memory");
        else            asm volatile("s_waitcnt vmcnt(0)" ::: "memory");
        __builtin_amdgcn_s_barrier();
        #pragma unroll
        for (int nn = 0; nn < 4; ++nn)
          #pragma unroll
          for (int kk = 0; kk < 2; ++kk)
            bfr[nn][kk] = lds_frag64(Bb, wc * 64 + nn * 16 + lr, kk * 32 + lg * 8);
      }
      bf16x8 af[2][2];
      #pragma unroll
      for (int mm = 0; mm < 2; ++mm)
        #pragma unroll
        for (int kk = 0; kk < 2; ++kk)
          af[mm][kk] = lds_frag64(Ab, wr * 128 + p * 32 + mm * 16 + lr, kk * 32 + lg * 8);
      asm volatile("s_waitcnt lgkmcnt(0)" ::: "memory");
      __builtin_amdgcn_sched_barrier(0);
      __builtin_amdgcn_s_setprio(1);
      #pragma unroll
      for (int mm = 0; mm < 2; ++mm)
        #pragma unroll
        for (int nn = 0; nn < 4; ++nn) {
          acc[p * 2 + mm][nn] = __builtin_amdgcn_mfma_f32_16x16x32_bf16(af[mm][0], bfr[nn][0], acc[p * 2 + mm][nn], 0, 0, 0);
          acc[p * 2 + mm][nn] = __builtin_amdgcn_mfma_f32_16x16x32_bf16(af[mm][1], bfr[nn][1], acc[p * 2 + mm][nn], 0, 0, 0);
        }
      __builtin_amdgcn_s_setprio(0);
    }
    __builtin_amdgcn_s_barrier();
  }

  #pragma unroll
  for (int mg = 0; mg < 8; ++mg) {
    #pragma unroll
    for (int nn = 0; nn < 4; ++nn) {
      int c = col0 + wc * 64 + nn * 16 + lr;
      int rb = row0 + wr * 128 + mg * 16 + lg * 4;
      float b = bias[c];
      #pragma unroll
      for (int j = 0; j < 4; ++j)
        out[(size_t)(rb + j) * N + c] = acc[mg][nn][j] + b;
    }
  }
}

// ---------------- fused attention: MFMA scores -> top-307 -> softmax -> MFMA PV ----------------
__global__ __launch_bounds__(256)
void attn_kernel(const __bf16* __restrict__ qm, const __bf16* __restrict__ km,
                 const __bf16* __restrict__ vt, __bf16* __restrict__ o) {
  __shared__ unsigned short sc16[16][SRS];
  __shared__ float rs[16];
  const int q0 = blockIdx.x * 16;
  const int hh = blockIdx.y;
  const int bb = blockIdx.z;
  const int tid = threadIdx.x;
  const int lane = tid & 63, w = tid >> 6;
  const int lr = lane & 15, lg = lane >> 4;

  const __bf16* qrow = qm + ((size_t)(bb * S_ + q0 + lr)) * D_ + hh * DK_;
  bf16x8 qf0 = *reinterpret_cast<const bf16x8*>(qrow + lg * 8);
  bf16x8 qf1 = *reinterpret_cast<const bf16x8*>(qrow + 32 + lg * 8);

  const __bf16* kbase = km + ((size_t)bb * S_) * D_ + hh * DK_;
  #pragma unroll 4
  for (int kt = 0; kt < 16; ++kt) {
    int key0 = kt * 64 + w * 16;
    const __bf16* krow = kbase + (size_t)(key0 + lr) * D_;
    bf16x8 kf0 = *reinterpret_cast<const bf16x8*>(krow + lg * 8);
    bf16x8 kf1 = *reinterpret_cast<const bf16x8*>(krow + 32 + lg * 8);
    f32x4v d = {0.0f, 0.0f, 0.0f, 0.0f};
    __builtin_amdgcn_s_setprio(1);
    d = __builtin_amdgcn_mfma_f32_16x16x32_bf16(qf0, kf0, d, 0, 0, 0);
    d = __builtin_amdgcn_mfma_f32_16x16x32_bf16(qf1, kf1, d, 0, 0, 0);
    __builtin_amdgcn_s_setprio(0);
    #pragma unroll
    for (int j = 0; j < 4; ++j) {
      unsigned int u = f32_to_bf16_bits(d[j] * 0.125f);
      u = (u & 0x8000u) ? (~u & 0xFFFFu) : (u | 0x8000u);
      sc16[lg * 4 + j][key0 + lr] = (unsigned short)u;
    }
  }
  __syncthreads();

  {
    int r = tid >> 4, tc = tid & 15;   // 16-lane row teams == DPP rows
    const unsigned int* srow = reinterpret_cast<const unsigned int*>(&sc16[r][0]);
    unsigned int wv[32];
    #pragma unroll
    for (int g = 0; g < 8; ++g) {
      uint4 t4 = *reinterpret_cast<const uint4*>(&srow[g * 64 + tc * 4]);
      wv[g * 4 + 0] = t4.x; wv[g * 4 + 1] = t4.y;
      wv[g * 4 + 2] = t4.z; wv[g * 4 + 3] = t4.w;
    }
    unsigned int umax = 0;
    #pragma unroll
    for (int i = 0; i < 32; ++i) {
      unsigned int a = wv[i] & 0xFFFFu, b = wv[i] >> 16;
      unsigned int mx = a > b ? a : b;
      umax = mx > umax ? mx : umax;
    }
    umax = red16umax(umax);
    unsigned int lo = 0;
    for (int bit = 15; bit >= 0; --bit) {
      unsigned int cs = (lo | (1u << bit)) << 16;
      int cnt = 0;
      #pragma unroll
      for (int i = 0; i < 32; ++i) {
        cnt += ((wv[i] << 16) >= cs) ? 1 : 0;
        cnt += (wv[i] >= cs) ? 1 : 0;
      }
      cnt = red16i(cnt);
      if (cnt >= KTOP) lo |= (1u << bit);
    }
    unsigned int um = (umax & 0x8000u) ? (umax ^ 0x8000u) : (~umax & 0xFFFFu);
    float mval = __uint_as_float(um << 16);

    __bf16* P = reinterpret_cast<__bf16*>(&sc16[r][0]);
    float lsum = 0.0f;
    #pragma unroll
    for (int g = 0; g < 8; ++g) {
      bf16x8 pk;
      #pragma unroll
      for (int e = 0; e < 8; ++e) {
        unsigned int wrd = wv[g * 4 + (e >> 1)];
        unsigned int u = (e & 1) ? (wrd >> 16) : (wrd & 0xFFFFu);
        float p = 0.0f;
        if (u >= lo) {
          unsigned int ub = (u & 0x8000u) ? (u ^ 0x8000u) : (~u & 0xFFFFu);
          p = __expf(__uint_as_float(ub << 16) - mval);
        }
        pk[e] = (__bf16)p;
        lsum += (float)pk[e];
      }
      *reinterpret_cast<bf16x8*>(&P[tc * 8 + g * 128]) = pk;
    }
    lsum = red16f(lsum);
    if (tc == 0) rs[r] = lsum;
  }
  __syncthreads();

  {
    const __bf16* P0 = reinterpret_cast<const __bf16*>(&sc16[0][0]);
    const __bf16* vbase = vt + ((size_t)bb * D_ + hh * DK_ + w * 16 + lr) * S_;
    const __bf16* prow = P0 + (size_t)lr * SRS;
    f32x4v oacc = {0.0f, 0.0f, 0.0f, 0.0f};
    #pragma unroll 4
    for (int kt = 0; kt < 32; ++kt) {
      bf16x8 a = *reinterpret_cast<const bf16x8*>(prow + kt * 32 + lg * 8);
      bf16x8 b = *reinterpret_cast<const bf16x8*>(vbase + kt * 32 + lg * 8);
      __builtin_amdgcn_s_setprio(1);
      oacc = __builtin_amdgcn_mfma_f32_16x16x32_bf16(a, b, oacc, 0, 0, 0);
      __builtin_amdgcn_s_setprio(0);
    }
    #pragma unroll
    for (int j = 0; j < 4; ++j) {
      int qr = lg * 4 + j;
      float ov = oacc[j] / rs[qr];
      o[((size_t)(bb * S_ + q0 + qr)) * D_ + hh * DK_ + w * 16 + lr] = (__bf16)ov;
    }
  }
}

extern "C" void kernel_launch(void* const* d_in, const int* in_sizes, int n_in,
                              void* d_out, int out_size, void* d_ws, size_t ws_size,
                              hipStream_t stream) {
  (void)in_sizes; (void)n_in; (void)out_size; (void)ws_size;
  const int*   x    = (const int*)d_in[0];
  const float* tok  = (const float*)d_in[1];
  const float* pos  = (const float*)d_in[2];
  const float* Wq   = (const float*)d_in[3];
  const float* bq   = (const float*)d_in[4];
  const float* Wk   = (const float*)d_in[5];
  const float* bk   = (const float*)d_in[6];
  const float* Wv   = (const float*)d_in[7];
  const float* bv   = (const float*)d_in[8];
  const float* Wo   = (const float*)d_in[9];
  const float* bo   = (const float*)d_in[10];
  const float* g1   = (const float*)d_in[11];
  const float* be1  = (const float*)d_in[12];
  const float* g2   = (const float*)d_in[13];
  const float* be2  = (const float*)d_in[14];
  const float* W1   = (const float*)d_in[15];
  const float* b1   = (const float*)d_in[16];
  const float* Wm   = (const float*)d_in[17];
  const float* bm   = (const float*)d_in[18];
  const float* W2   = (const float*)d_in[19];
  const float* b2   = (const float*)d_in[20];
  const float* Wout = (const float*)d_in[21];
  const float* bout = (const float*)d_in[22];
  float* logits = (float*)d_out;

  const int M = B_ * S_;  // 4096
  float* ws = (float*)d_ws;
  float* h    = ws;
  float* bqkv = h + (size_t)M * D_;
  __bf16* y16  = (__bf16*)(bqkv + (size_t)L_ * 1536);
  __bf16* f1b  = y16  + (size_t)M * D_;
  __bf16* f2b  = f1b  + (size_t)M * DFF_;
  __bf16* qb16 = f2b  + (size_t)M * DFF_;
  __bf16* kb16 = qb16 + (size_t)M * D_;
  __bf16* vt16 = kb16 + (size_t)M * D_;
  __bf16* ob16 = vt16 + (size_t)M * D_;
  __bf16* h16  = ob16 + (size_t)M * D_;
  __bf16* WqkvT = h16 + (size_t)M * D_;
  __bf16* WoT  = WqkvT + (size_t)L_ * 1536 * D_;
  __bf16* W1T  = WoT  + (size_t)L_ * D_ * D_;
  __bf16* WmT  = W1T  + (size_t)L_ * D_ * DFF_;
  __bf16* W2T  = WmT  + (size_t)L_ * DFF_ * DFF_;
  __bf16* WoutT = W2T + (size_t)L_ * D_ * DFF_;

  const long DD = (long)D_ * D_;
  transpose_bf16_kernel<<<dim3(D_/32,  D_/32,   L_), 256, 0, stream>>>(Wq, WqkvT,            D_, D_, DD, 1536L*D_);
  transpose_bf16_kernel<<<dim3(D_/32,  D_/32,   L_), 256, 0, stream>>>(Wk, WqkvT + 512*512,  D_, D_, DD, 1536L*D_);
  transpose_bf16_kernel<<<dim3(D_/32,  D_/32,   L_), 256, 0, stream>>>(Wv, WqkvT + 1024*512, D_, D_, DD, 1536L*D_);
  transpose_bf16_kernel<<<dim3(D_/32,  D_/32,   L_), 256, 0, stream>>>(Wo, WoT, D_, D_, DD, DD);
  transpose_bf16_kernel<<<dim3(DFF_/32, D_/32,  L_), 256, 0, stream>>>(W1, W1T, D_, DFF_, (long)D_*DFF_, (long)D_*DFF_);
  transpose_bf16_kernel<<<dim3(DFF_/32, DFF_/32,L_), 256, 0, stream>>>(Wm, WmT, DFF_, DFF_, (long)DFF_*DFF_, (long)DFF_*DFF_);
  transpose_bf16_kernel<<<dim3(D_/32,  DFF_/32, L_), 256, 0, stream>>>(W2, W2T, DFF_, D_, (long)D_*DFF_, (long)D_*DFF_);
  transpose_bf16_kernel<<<dim3(V_/32,  D_/32,   1 ), 256, 0, stream>>>(Wout, WoutT, D_, V_, (long)D_*V_, (long)D_*V_);
  concat_bias_kernel<<<(L_*1536)/256, 256, 0, stream>>>(bq, bk, bv, bqkv);

  embed_kernel<<<M, 128, 0, stream>>>(x, tok, pos, h);

  for (int l = 0; l < L_; ++l) {
    ln_kernel<<<M, 256, 0, stream>>>(h, g1 + l * D_, be1 + l * D_, y16);
    gemm_bf16_kernel<4,false,false,true><<<dim3((M/BM) * (1536/BN)), 256, 0, stream>>>(
        y16, WqkvT + (size_t)l * 1536 * D_, bqkv + l * 1536, nullptr,
        qb16, kb16, vt16, M, 1536, D_);
    attn_kernel<<<dim3(S_/16, H_, B_), 256, 0, stream>>>(qb16, kb16, vt16, ob16);
    gemm64_kernel<0,true><<<dim3(M/64, D_/BN), 256, 0, stream>>>(
        ob16, WoT + (size_t)l * DD, bo + l * D_, h, h, nullptr, M, D_, D_);
    ln_kernel<<<M, 256, 0, stream>>>(h, g2 + l * D_, be2 + l * D_, y16);
    gemm_bf16_kernel<1,true,false,true><<<dim3((M/BM) * (DFF_/BN)), 256, 0, stream>>>(
        y16, W1T + (size_t)l * D_ * DFF_, b1 + l * DFF_, nullptr, f1b, nullptr, nullptr, M, DFF_, D_);
    gemm_bf16_kernel<1,true,false,true><<<dim3((M/BM) * (DFF_/BN)), 256, 0, stream>>>(
        f1b, WmT + (size_t)l * DFF_ * DFF_, bm + l * DFF_, nullptr, f2b, nullptr, nullptr, M, DFF_, DFF_);
    gemm64_kernel<3,true><<<dim3(M/64, D_/BN), 256, 0, stream>>>(
        f2b, W2T + (size_t)l * D_ * DFF_, b2 + l * D_, h, h, h16, M, D_, DFF_);
  }
  gemm_head_kernel<<<dim3((M/256) * (V_/256)), 512, 0, stream>>>(
      h16, WoutT, bout, logits, M, V_, D_);
}